// Round 11
// baseline (787.983 us; speedup 1.0000x reference)
//
#include <hip/hip_runtime.h>
#include <hip/hip_bf16.h>

// RiemannianGraph_HRSNN, MFMA version. B=2048, T=15, N=64. All I/O f32.
// R16: 2-BATCH BLOCK. R15 (isolation) PASSED -> LDS-frag mechanism sound,
// and pinned R7/R8's failure to the (512,4)+LDS-frag combination exactly
// (R8 == R15 except launch bounds; deterministic compile -> that combo is
// closed). The occupancy goal never needed it: R16 keeps R10's REGISTER-
// frag text verbatim (96 VGPR, 0.375-stable across 6 recompiles incl. the
// R6 spill build) and gets 16 waves/CU via a 1024-thread block processing
// TWO batches: half hw=tid>>9 runs batch 2*blockIdx+hw on its own LDS bank
// (UBUF/Xt/LxS/Lsum/folds duplicated [2]; WgF shared, weight-derived).
// __launch_bounds__(1024,4): 1 block/CU, VGPR cap 128 >= 96 -> no spill
// (R6's failure mode), LDS 68608 < 160K. Block-wide barriers over-sync the
// independent halves (harmless); 4 waves/SIMD interleave two batches ->
// latency hidden ~2x, barrier stalls amortized over 2 batches.
// Decoder: R10 champion verbatim.
//
// Main-kernel math (unchanged from R4):
//   L 3-part x S1(exact)            -> 2^-27
//   M 3-part x Wg2 3-part (6 terms) -> ~2^-24
//   S1(exact) x Ws2 2-part          -> 2^-18 (no threshold downstream)
//   L 3-part x Xt 2-part (3 terms)  -> ~2^-17
// MFMA layouts: A[row=lane&15][k=8*(lane>>4)+j], B[k=8q+j][col=lane&15],
// C/D[row=4*(lane>>4)+reg][col=lane&15].

typedef __attribute__((ext_vector_type(8))) short s16x8;
typedef __attribute__((ext_vector_type(4))) float f32x4;
#define MFMA16(a, b, c) __builtin_amdgcn_mfma_f32_16x16x32_bf16(a, b, c, 0, 0, 0)

__device__ __forceinline__ short f2bs(float x) {
  union { __hip_bfloat16 h; short s; } u; u.h = __float2bfloat16(x); return u.s;
}
__device__ __forceinline__ float bs2f(short s) {
  union { short s; __hip_bfloat16 h; } u; u.s = s; return __bfloat162float(u.h);
}

#define LIF_STEP(mem, beta, thr, cur, spksum)                \
  {                                                          \
    float r_ = ((mem) > (thr)) ? (thr) : 0.0f;               \
    (mem) = (beta) * (mem) + (cur) - r_;                     \
    (spksum) += (((mem) - (thr)) > 0.0f) ? 1.0f : 0.0f;      \
  }

#define LFS 68      // Lf row stride (f32 words)
#define RS  36      // S1row / Mrow row stride

__global__ __launch_bounds__(1024, 4)
void hrsnn_main(const float* __restrict__ Lg,  const float* __restrict__ Xg,
                const float* __restrict__ Wp,  const float* __restrict__ bp,
                const float* __restrict__ Wg1, const float* __restrict__ bg1,
                const float* __restrict__ Ws1, const float* __restrict__ bs1,
                const float* __restrict__ Wg2, const float* __restrict__ bg2,
                const float* __restrict__ Ws2, const float* __restrict__ bs2,
                unsigned int* __restrict__ dp_out)
{
  // Per-half UBUF: union of Lf[64][68] (init only) with S1row[64][36]+Mrow[64][36]
  __shared__ __align__(16) float UBUF[2][4608];
  __shared__ __align__(16) short WgF[4 * 3 * 64 * 8];   // Wg2 frags (shared, weight-derived)
  __shared__ __align__(16) unsigned int XtHL[2][960];   // packed (hi<<16|lo) bf16 of Xt
  __shared__ __align__(16) float Xtf[2][960];
  __shared__ float LxS[2][64], LsumS[2][64];
  __shared__ float u1A[2][32], cb1A[2][32], us1v[2][32], cs1v[2][32];
  __shared__ float u2gA[2][64], c2gA[2][64], u2sA[2][64], cs2A[2][64];

  const int tid = threadIdx.x;
  const int hw = tid >> 9;                  // batch half within block
  const int t5 = tid & 511;                 // intra-half thread id (R10's tid)
  const int b = blockIdx.x * 2 + hw;
  const int l = t5 & 63, w = t5 >> 6;
  const int p = w >> 1, h = w & 1;          // row-stripe / col-half
  const int q = l >> 4, c = l & 15;
  const int R = 16 * p;

  float* const Lf    = UBUF[hw];            // init only
  float* const S1row = UBUF[hw];            // [64][RS]
  float* const Mrow  = UBUF[hw] + 2304;     // [64][RS]

  // ================= init 1: stage Lf, Xt (split), small weight folds ========
  const float* Lb = Lg + (size_t)b * 4096;
#pragma unroll
  for (int k = 0; k < 2; k++) {
    const int i4 = t5 + 512 * k;                  // float4 index in [0,1024)
    const float4 v = *(const float4*)&Lb[i4 * 4];
    *(float4*)&Lf[(i4 >> 4) * LFS + (i4 & 15) * 4] = v;
  }
  const float* Xb = Xg + (size_t)b * 960;
  for (int i = t5; i < 960; i += 512) {
    const float x = Xb[i];
    const short hs = f2bs(x);
    const short ls = f2bs(x - bs2f(hs));
    XtHL[hw][i] = ((unsigned int)(unsigned short)hs << 16) | (unsigned short)ls;
    Xtf[hw][i] = x;
  }
  if (t5 < 32) {
    const int f = t5;
    float a = 0.f, bb = 0.f, cc = 0.f, d = 0.f;
    for (int k = 0; k < 16; k++) {
      const float wp = Wp[k], bpv = bp[k];
      const float wg = Wg1[k * 32 + f], ws = Ws1[k * 32 + f];
      a += wp * wg; bb += bpv * wg;
      cc += wp * ws; d += bpv * ws;
    }
    u1A[hw][f] = a; cb1A[hw][f] = bb;
    us1v[hw][f] = cc; cs1v[hw][f] = d + bs1[f];
  }
  __syncthreads();

  // ================= init 2: Lsum, L A-frags, WgF, Ws2 frags ================
  {
    const int n = t5 >> 3, o = t5 & 7;
    const float4 a4 = *(const float4*)&Lf[n * LFS + 8 * o];
    const float4 b4 = *(const float4*)&Lf[n * LFS + 8 * o + 4];
    float ps = a4.x + a4.y + a4.z + a4.w + b4.x + b4.y + b4.z + b4.w;
    ps += __shfl_xor(ps, 1, 64);
    ps += __shfl_xor(ps, 2, 64);
    ps += __shfl_xor(ps, 4, 64);
    if (o == 0) LsumS[hw][n] = ps;
  }
  // L A-frags: 3 parts x 2 K-slices (K=64), in registers (R10 verbatim)
  s16x8 Lh[2], Lm[2], Ll[2];
#pragma unroll
  for (int s = 0; s < 2; s++) {
    const float* rp = &Lf[(R + c) * LFS + 32 * s + 8 * q];
    const float4 v0 = *(const float4*)rp;
    const float4 v1 = *(const float4*)(rp + 4);
    float v[8] = {v0.x, v0.y, v0.z, v0.w, v1.x, v1.y, v1.z, v1.w};
#pragma unroll
    for (int j = 0; j < 8; j++) {
      const short hh = f2bs(v[j]);       const float r1 = v[j] - bs2f(hh);
      const short mm = f2bs(r1);         const float r2 = r1 - bs2f(mm);
      Lh[s][j] = hh; Lm[s][j] = mm; Ll[s][j] = f2bs(r2);
    }
  }
  // Wg2 fragment store (shared; built by half 0 exactly as R10's waves 0-7)
  if (hw == 0) {
    const int tt = w & 3;
    float v[8];
#pragma unroll
    for (int j = 0; j < 8; j++) v[j] = Wg2[(8 * q + j) * 64 + 16 * tt + c];
    if (w < 4) {
      s16x8 fh, fm;
#pragma unroll
      for (int j = 0; j < 8; j++) {
        const short hh = f2bs(v[j]);
        fh[j] = hh; fm[j] = f2bs(v[j] - bs2f(hh));
      }
      *(s16x8*)&WgF[((tt * 3 + 0) * 64 + l) * 8] = fh;
      *(s16x8*)&WgF[((tt * 3 + 1) * 64 + l) * 8] = fm;
    } else {
      s16x8 fl;
#pragma unroll
      for (int j = 0; j < 8; j++) {
        const short hh = f2bs(v[j]);     const float r1 = v[j] - bs2f(hh);
        const short mm = f2bs(r1);       const float r2 = r1 - bs2f(mm);
        fl[j] = f2bs(r2);
      }
      *(s16x8*)&WgF[((tt * 3 + 2) * 64 + l) * 8] = fl;
    }
  }
  // Ws2 frags (2-part) for this wave's two g-tiles, in registers (R10 verbatim)
  s16x8 WsH[2], WsL[2];
#pragma unroll
  for (int i = 0; i < 2; i++) {
    const int g0 = 32 * h + 16 * i;
#pragma unroll
    for (int j = 0; j < 8; j++) {
      const float x = Ws2[(8 * q + j) * 64 + g0 + c];
      const short hh = f2bs(x);
      WsH[i][j] = hh; WsL[i][j] = f2bs(x - bs2f(hh));
    }
  }
  __syncthreads();

  // ================= init 3: layer-2 derived vectors =========================
  if (t5 < 64) {
    const int g = t5;
    float a = 0.f, bb = 0.f, cc = 0.f, d = 0.f;
    for (int f = 0; f < 32; f++) {
      const float wg = Wg2[f * 64 + g], ws = Ws2[f * 64 + g];
      a += us1v[hw][f] * wg; bb += cs1v[hw][f] * wg;
      cc += us1v[hw][f] * ws; d += cs1v[hw][f] * ws;
    }
    u2gA[hw][g] = a; c2gA[hw][g] = bb; u2sA[hw][g] = cc; cs2A[hw][g] = d + bs2[g];
  }
  __syncthreads();

  // ================= init 4: per-lane constants (registers, R10 verbatim) ====
  float u2g2[2], u2s2[2], cs22[2], c2c[2][4];
#pragma unroll
  for (int i = 0; i < 2; i++) {
    const int g = 32 * h + 16 * i + c;
    u2g2[i] = u2gA[hw][g]; u2s2[i] = u2sA[hw][g]; cs22[i] = cs2A[hw][g];
    const float cg = c2gA[hw][g], bg = bg2[g];
#pragma unroll
    for (int r = 0; r < 4; r++) c2c[i][r] = LsumS[hw][R + 4 * q + r] * cg + bg;
  }
  // LIF-1 mapping: f = t5&31, nb = t5>>5, cells n = nb + 16j
  const int f1 = t5 & 31, nb = t5 >> 5;
  const float u1f = u1A[hw][f1];
  float k1c[4];
  {
    const float cb = cb1A[hw][f1], bg = bg1[f1];
#pragma unroll
    for (int j = 0; j < 4; j++) k1c[j] = LsumS[hw][nb + 16 * j] * cb + bg;
  }

  // ================= state registers =========================================
  float m1a[4], m1n[4], m1m[4];
#pragma unroll
  for (int j = 0; j < 4; j++) { m1a[j] = 0.f; m1n[j] = 0.f; m1m[j] = 0.f; }
  float m2a[2][4], m2n[2][4], m2m[2][4], mli[2][4], dpa[2][4];
#pragma unroll
  for (int i = 0; i < 2; i++)
#pragma unroll
    for (int r = 0; r < 4; r++) {
      m2a[i][r] = 0.f; m2n[i][r] = 0.f; m2m[i][r] = 0.f;
      mli[i][r] = 0.f; dpa[i][r] = 0.f;
    }

  const f32x4 fz = {0.f, 0.f, 0.f, 0.f};
  __syncthreads();   // Lf dead; UBUF becomes S1row/Mrow

  // ================= time loop: 3 barriers/step ==============================
  // Barrier safety per half (block-wide barriers are a superset): D(t) reads
  // Mrow; C(t+1) writes Mrow only after alpha(t+1)+beta(t+1). Same
  // two-barrier separation covers C(t) S1row reads vs B(t+1) writes and
  // B(t) LxS reads vs A(t+1) writes. Halves touch disjoint LDS (WgF is
  // read-only after init-2's barrier).
  for (int t = 0; t < 15; t++) {
    // ---- phase A: Lx = L@Xt via MFMA broadcast (all B-cols = Xt) ----
    f32x4 lx = fz;
#pragma unroll
    for (int s = 0; s < 2; s++) {
      const unsigned int* xw = &XtHL[hw][t * 64 + 32 * s + 8 * q];
      const uint4 w0 = *(const uint4*)xw;
      const uint4 w1 = *(const uint4*)(xw + 4);
      unsigned int wv[8] = {w0.x, w0.y, w0.z, w0.w, w1.x, w1.y, w1.z, w1.w};
      s16x8 bh, bl;
#pragma unroll
      for (int j = 0; j < 8; j++) {
        bh[j] = (short)(wv[j] >> 16);
        bl[j] = (short)(wv[j] & 0xffff);
      }
      lx = MFMA16(Lh[s], bh, lx);
      lx = MFMA16(Lm[s], bh, lx);
      lx = MFMA16(Lh[s], bl, lx);
    }
    if (h == 0 && c == 0) {
#pragma unroll
      for (int r = 0; r < 4; r++) LxS[hw][R + 4 * q + r] = lx[r];
    }
    __syncthreads();   // alpha

    // ---- phase B: layer-1 LIF -> S1row ----
#pragma unroll
    for (int j = 0; j < 4; j++) {
      const int n = nb + 16 * j;
      const float cur = LxS[hw][n] * u1f + k1c[j];
      float ss = 0.f;
      LIF_STEP(m1a[j], 0.8f, 0.8f, cur, ss);
      LIF_STEP(m1n[j], 0.9f, 1.0f, cur, ss);
      LIF_STEP(m1m[j], 0.95f, 1.5f, cur, ss);
      S1row[n * RS + f1] = ss;
    }
    __syncthreads();   // beta

    // ---- phase C: M = L@S1 (3-part L), spk2d = S1@Ws2 (2-part W) ----
    f32x4 macc = fz;
#pragma unroll
    for (int s = 0; s < 2; s++) {
      s16x8 bS;
#pragma unroll
      for (int j = 0; j < 8; j++)
        bS[j] = f2bs(S1row[(32 * s + 8 * q + j) * RS + 16 * h + c]);
      macc = MFMA16(Lh[s], bS, macc);
      macc = MFMA16(Lm[s], bS, macc);
      macc = MFMA16(Ll[s], bS, macc);
    }
#pragma unroll
    for (int r = 0; r < 4; r++) Mrow[(R + 4 * q + r) * RS + 16 * h + c] = macc[r];

    f32x4 sacc[2];
    {
      const float* rp = &S1row[(R + c) * RS + 8 * q];
      const float4 v0 = *(const float4*)rp;
      const float4 v1 = *(const float4*)(rp + 4);
      const float v[8] = {v0.x, v0.y, v0.z, v0.w, v1.x, v1.y, v1.z, v1.w};
      s16x8 aS;
#pragma unroll
      for (int j = 0; j < 8; j++) aS[j] = f2bs(v[j]);
#pragma unroll
      for (int i = 0; i < 2; i++) {
        sacc[i] = MFMA16(aS, WsH[i], fz);
        sacc[i] = MFMA16(aS, WsL[i], sacc[i]);
      }
    }
    __syncthreads();   // gamma

    // ---- phase D: cur2 = M@Wg2 (6-term) + LIF-2 (all in registers) ----
    s16x8 aMh, aMm, aMl;
    {
      const float* rp = &Mrow[(R + c) * RS + 8 * q];
      const float4 v0 = *(const float4*)rp;
      const float4 v1 = *(const float4*)(rp + 4);
      const float v[8] = {v0.x, v0.y, v0.z, v0.w, v1.x, v1.y, v1.z, v1.w};
#pragma unroll
      for (int j = 0; j < 8; j++) {
        const short hh = f2bs(v[j]);     const float r1 = v[j] - bs2f(hh);
        const short mm = f2bs(r1);       const float r2 = r1 - bs2f(mm);
        aMh[j] = hh; aMm[j] = mm; aMl[j] = f2bs(r2);
      }
    }
    float xtn[4];
#pragma unroll
    for (int r = 0; r < 4; r++) xtn[r] = Xtf[hw][t * 64 + R + 4 * q + r];

#pragma unroll
    for (int i = 0; i < 2; i++) {
      const int tt = 2 * h + i;
      const s16x8 bGh = *(const s16x8*)&WgF[((tt * 3 + 0) * 64 + l) * 8];
      const s16x8 bGm = *(const s16x8*)&WgF[((tt * 3 + 1) * 64 + l) * 8];
      const s16x8 bGl = *(const s16x8*)&WgF[((tt * 3 + 2) * 64 + l) * 8];
      f32x4 cacc = fz;
      cacc = MFMA16(aMh, bGh, cacc);
      cacc = MFMA16(aMh, bGm, cacc);
      cacc = MFMA16(aMm, bGh, cacc);
      cacc = MFMA16(aMh, bGl, cacc);
      cacc = MFMA16(aMm, bGm, cacc);
      cacc = MFMA16(aMl, bGh, cacc);
#pragma unroll
      for (int r = 0; r < 4; r++) {
        const float cur2 = cacc[r] + lx[r] * u2g2[i] + c2c[i][r];
        float ss = 0.f;
        LIF_STEP(m2a[i][r], 0.8f, 0.8f, cur2, ss);
        LIF_STEP(m2n[i][r], 0.9f, 1.0f, cur2, ss);
        LIF_STEP(m2m[i][r], 0.95f, 1.5f, cur2, ss);
        const float spk2 = ss + sacc[i][r] + xtn[r] * u2s2[i] + cs22[i];
        mli[i][r] = 0.9f * mli[i][r] + spk2;
      }
    }
    if (t < 5) {
#pragma unroll
      for (int i = 0; i < 2; i++)
#pragma unroll
        for (int r = 0; r < 4; r++) dpa[i][r] -= mli[i][r];
    } else if (t >= 10) {
#pragma unroll
      for (int i = 0; i < 2; i++)
#pragma unroll
        for (int r = 0; r < 4; r++) dpa[i][r] += mli[i][r];
    }
    // no end-of-step barrier (see proof above)
  }

  // ---- dp_feat = (sum_last5 - sum_first5)/5, packed split-bf16 ----
  unsigned int* dpb = dp_out + (size_t)b * 4096;
#pragma unroll
  for (int i = 0; i < 2; i++) {
    const int g = 32 * h + 16 * i + c;
#pragma unroll
    for (int r = 0; r < 4; r++) {
      const int n = R + 4 * q + r;
      const float v = dpa[i][r] * 0.2f;
      const short hh = f2bs(v);
      const short ll = f2bs(v - bs2f(hh));
      dpb[n * 64 + g] = ((unsigned int)(unsigned short)hh << 16) | (unsigned short)ll;
    }
  }
}

// Decoder v2 (R10 champion, verbatim): out = relu(dp @ W1 + b1) @ W2 + b2.
// 256 blocks x 512 threads (8 waves = 2/SIMD). Block = (16-batch group g) x
// (64-col half hb). Wave (tw, kh): col sub-tile tw, K-half kh (64 slices).
// Partial acc -> LDS Hp[2], one barrier, bias+relu+GEMM2. Second GEMM:
// 64-col partial per block via f32 atomicAdd (2 commutative contributions
// per element; out zeroed by hipMemsetAsync; each block adds b2/2).

#define DEC_STEP(S, CA0, CA1)                                          \
  {                                                                    \
    const unsigned int av[8] = {(CA0).x, (CA0).y, (CA0).z, (CA0).w,    \
                                (CA1).x, (CA1).y, (CA1).z, (CA1).w};   \
    s16x8 Ah, Al, Bh, Bl;                                              \
    _Pragma("unroll")                                                  \
    for (int j = 0; j < 8; j++) {                                      \
      Ah[j] = (short)(av[j] >> 16);                                    \
      Al[j] = (short)(av[j] & 0xffff);                                 \
      const float x = bcol2[(32 * (S) + j) * 128];                     \
      const short hh = f2bs(x);                                        \
      Bh[j] = hh; Bl[j] = f2bs(x - bs2f(hh));                          \
    }                                                                  \
    acc = MFMA16(Ah, Bh, acc);                                         \
    acc = MFMA16(Al, Bh, acc);                                         \
    acc = MFMA16(Ah, Bl, acc);                                         \
  }

#define DEC_SLOT(S, BUF, NXT)                                          \
  {                                                                    \
    const uint4 c0 = BUF[0], c1 = BUF[1];                              \
    if ((NXT) < 64) {                                                  \
      BUF[0] = *(const uint4*)(arow2 + 32 * (NXT));                    \
      BUF[1] = *(const uint4*)(arow2 + 32 * (NXT) + 4);                \
    }                                                                  \
    DEC_STEP(S, c0, c1);                                               \
  }

__global__ __launch_bounds__(512, 2)
void hrsnn_decoder(const unsigned int* __restrict__ dpq, const float* __restrict__ W1,
                   const float* __restrict__ b1, const float* __restrict__ W2,
                   const float* __restrict__ b2, float* __restrict__ out)
{
  __shared__ __align__(16) float Hp[2][16][68];   // partial acc per K-half
  const int tid = threadIdx.x;
  const int l = tid & 63, w = tid >> 6;
  const int tw = w & 3, kh = w >> 2;           // col sub-tile / K half
  const int g  = blockIdx.x >> 1;              // batch group (16 rows)
  const int hb = blockIdx.x & 1;               // col half (64 of 128)
  const int q = l >> 4, c = l & 15;
  const int col = 64 * hb + 16 * tw + c;

  const unsigned int* arow2 = dpq + (size_t)(g * 16 + c) * 4096 + 2048 * kh + 8 * q;
  const float* bcol2 = W1 + (size_t)(2048 * kh + 8 * q) * 128 + col;

  f32x4 acc = {0.f, 0.f, 0.f, 0.f};
  uint4 A0[2], A1[2], A2[2], A3[2];
  A0[0] = *(const uint4*)(arow2);       A0[1] = *(const uint4*)(arow2 + 4);
  A1[0] = *(const uint4*)(arow2 + 32);  A1[1] = *(const uint4*)(arow2 + 36);
  A2[0] = *(const uint4*)(arow2 + 64);  A2[1] = *(const uint4*)(arow2 + 68);
  A3[0] = *(const uint4*)(arow2 + 96);  A3[1] = *(const uint4*)(arow2 + 100);
  for (int sl = 0; sl < 64; sl += 4) {
    DEC_SLOT(sl,     A0, sl + 4);
    DEC_SLOT(sl + 1, A1, sl + 5);
    DEC_SLOT(sl + 2, A2, sl + 6);
    DEC_SLOT(sl + 3, A3, sl + 7);
  }

#pragma unroll
  for (int r = 0; r < 4; r++) Hp[kh][4 * q + r][16 * tw + c] = acc[r];
  __syncthreads();

  if (tid < 64) {
    const int i = tid >> 2, o = tid & 3;
    float s = 0.5f * b2[o];
    const float* b1h = b1 + 64 * hb;
    const float* w2 = W2 + (64 * hb) * 4 + o;
    for (int k = 0; k < 64; k++) {
      float hv = Hp[0][i][k] + Hp[1][i][k] + b1h[k];
      hv = hv > 0.f ? hv : 0.f;
      s += hv * w2[k * 4];
    }
    atomicAdd(&out[(size_t)(g * 16 + i) * 4 + o], s);
  }
}

extern "C" void kernel_launch(void* const* d_in, const int* in_sizes, int n_in,
                              void* d_out, int out_size, void* d_ws, size_t ws_size,
                              hipStream_t stream)
{
  const float* Lg  = (const float*)d_in[0];
  const float* Xg  = (const float*)d_in[1];
  const float* Wp  = (const float*)d_in[2];
  const float* bp  = (const float*)d_in[3];
  const float* Wg1 = (const float*)d_in[4];
  const float* bg1 = (const float*)d_in[5];
  const float* Ws1 = (const float*)d_in[6];
  const float* bs1 = (const float*)d_in[7];
  const float* Wg2 = (const float*)d_in[8];
  const float* bg2 = (const float*)d_in[9];
  const float* Ws2 = (const float*)d_in[10];
  const float* bs2 = (const float*)d_in[11];
  const float* W1  = (const float*)d_in[12];
  const float* b1  = (const float*)d_in[13];
  const float* W2  = (const float*)d_in[14];
  const float* b2  = (const float*)d_in[15];

  unsigned int* dpq = (unsigned int*)d_ws;  // 2048*4096 packed uint = 32 MB
  float* out = (float*)d_out;               // [2048, 4] f32

  hipLaunchKernelGGL(hrsnn_main, dim3(1024), dim3(1024), 0, stream,
                     Lg, Xg, Wp, bp, Wg1, bg1, Ws1, bs1, Wg2, bg2, Ws2, bs2, dpq);
  hipMemsetAsync(out, 0, (size_t)2048 * 4 * sizeof(float), stream);
  hipLaunchKernelGGL(hrsnn_decoder, dim3(256), dim3(512), 0, stream,
                     dpq, W1, b1, W2, b2, out);
}

// Round 12
// 427.962 us; speedup vs baseline: 1.8412x; 1.8412x over previous
//
#include <hip/hip_runtime.h>
#include <hip/hip_bf16.h>

// RiemannianGraph_HRSNN, MFMA version. B=2048, T=15, N=64. All I/O f32.
// R17: BARRIER CUT 3->2 per step. R16 closed the occupancy door for good
// (combined VGPR+AGPR ~160 > the 128 cap of any 4-wave/SIMD config ->
// forced spills, FETCH 1.9GB, 665us; the spill-free LDS-frag variant under
// a reg cap is the R7/R8 correctness lottery). R17 attacks latency at
// unchanged occupancy: phase A's MFMA-broadcast already leaves
// lx[r] = Lx[R+4q+r] in EVERY lane's registers (all B-cols = Xt), so LIF-1
// is remapped to thread (p,h,q,c) handling cells (rows R+4q+r, f=16h+c) --
// cur = lx[r]*u1f + k1c[r] is register-only, and the alpha barrier + LxS
// array are DELETED (45 -> 30 barriers). Per-cell cur sequences are
// bit-identical (same inputs, same fma-contraction expression form; only
// the owning thread changes). Barrier safety at 2/step: one barrier
// suffices between reads and subsequent writes -- C(t) S1row reads ->
// gamma(t) -> B(t+1) writes; D(t) Mrow reads -> beta(t+1) -> C(t+1)
// writes; B(t) writes -> beta(t) -> C(t) reads. Decoder: R10 verbatim.
//
// Main-kernel math (unchanged from R4):
//   L 3-part x S1(exact)            -> 2^-27
//   M 3-part x Wg2 3-part (6 terms) -> ~2^-24
//   S1(exact) x Ws2 2-part          -> 2^-18 (no threshold downstream)
//   L 3-part x Xt 2-part (3 terms)  -> ~2^-17
// MFMA layouts: A[row=lane&15][k=8*(lane>>4)+j], B[k=8q+j][col=lane&15],
// C/D[row=4*(lane>>4)+reg][col=lane&15].

typedef __attribute__((ext_vector_type(8))) short s16x8;
typedef __attribute__((ext_vector_type(4))) float f32x4;
#define MFMA16(a, b, c) __builtin_amdgcn_mfma_f32_16x16x32_bf16(a, b, c, 0, 0, 0)

__device__ __forceinline__ short f2bs(float x) {
  union { __hip_bfloat16 h; short s; } u; u.h = __float2bfloat16(x); return u.s;
}
__device__ __forceinline__ float bs2f(short s) {
  union { short s; __hip_bfloat16 h; } u; u.s = s; return __bfloat162float(u.h);
}

#define LIF_STEP(mem, beta, thr, cur, spksum)                \
  {                                                          \
    float r_ = ((mem) > (thr)) ? (thr) : 0.0f;               \
    (mem) = (beta) * (mem) + (cur) - r_;                     \
    (spksum) += (((mem) - (thr)) > 0.0f) ? 1.0f : 0.0f;      \
  }

#define LFS 68      // Lf row stride (f32 words)
#define RS  36      // S1row / Mrow row stride

__global__ __launch_bounds__(512, 2)
void hrsnn_main(const float* __restrict__ Lg,  const float* __restrict__ Xg,
                const float* __restrict__ Wp,  const float* __restrict__ bp,
                const float* __restrict__ Wg1, const float* __restrict__ bg1,
                const float* __restrict__ Ws1, const float* __restrict__ bs1,
                const float* __restrict__ Wg2, const float* __restrict__ bg2,
                const float* __restrict__ Ws2, const float* __restrict__ bs2,
                unsigned int* __restrict__ dp_out)
{
  // UBUF: union of Lf[64][68] (init only, 4352) with S1row[64][36]+Mrow[64][36]
  __shared__ __align__(16) float UBUF[4608];
  float* const Lf    = UBUF;          // init only
  float* const S1row = UBUF;          // [64][RS]
  float* const Mrow  = UBUF + 2304;   // [64][RS]
  __shared__ __align__(16) short WgF[4 * 3 * 64 * 8];   // Wg2 frags [tile][part][lane][8]
  __shared__ __align__(16) unsigned int XtHL[960];      // packed (hi<<16|lo) bf16 of Xt
  __shared__ __align__(16) float Xtf[960];
  __shared__ float LsumS[64];
  __shared__ float u1A[32], cb1A[32], us1v[32], cs1v[32];
  __shared__ float u2gA[64], c2gA[64], u2sA[64], cs2A[64];

  const int tid = threadIdx.x;
  const int b = blockIdx.x;
  const int l = tid & 63, w = tid >> 6;
  const int p = w >> 1, h = w & 1;          // row-stripe / col-half
  const int q = l >> 4, c = l & 15;
  const int R = 16 * p;

  // ================= init 1: stage Lf, Xt (split), small weight folds ========
  const float* Lb = Lg + (size_t)b * 4096;
#pragma unroll
  for (int k = 0; k < 2; k++) {
    const int i4 = tid + 512 * k;                 // float4 index in [0,1024)
    const float4 v = *(const float4*)&Lb[i4 * 4];
    *(float4*)&Lf[(i4 >> 4) * LFS + (i4 & 15) * 4] = v;
  }
  const float* Xb = Xg + (size_t)b * 960;
  for (int i = tid; i < 960; i += 512) {
    const float x = Xb[i];
    const short hs = f2bs(x);
    const short ls = f2bs(x - bs2f(hs));
    XtHL[i] = ((unsigned int)(unsigned short)hs << 16) | (unsigned short)ls;
    Xtf[i] = x;
  }
  if (tid < 32) {
    const int f = tid;
    float a = 0.f, bb = 0.f, cc = 0.f, d = 0.f;
    for (int k = 0; k < 16; k++) {
      const float wp = Wp[k], bpv = bp[k];
      const float wg = Wg1[k * 32 + f], ws = Ws1[k * 32 + f];
      a += wp * wg; bb += bpv * wg;
      cc += wp * ws; d += bpv * ws;
    }
    u1A[f] = a; cb1A[f] = bb;
    us1v[f] = cc; cs1v[f] = d + bs1[f];
  }
  __syncthreads();

  // ================= init 2: Lsum, L A-frags, WgF, Ws2 frags ================
  {
    const int n = tid >> 3, o = tid & 7;
    const float4 a4 = *(const float4*)&Lf[n * LFS + 8 * o];
    const float4 b4 = *(const float4*)&Lf[n * LFS + 8 * o + 4];
    float ps = a4.x + a4.y + a4.z + a4.w + b4.x + b4.y + b4.z + b4.w;
    ps += __shfl_xor(ps, 1, 64);
    ps += __shfl_xor(ps, 2, 64);
    ps += __shfl_xor(ps, 4, 64);
    if (o == 0) LsumS[n] = ps;
  }
  // L A-frags: 3 parts x 2 K-slices (K=64)
  s16x8 Lh[2], Lm[2], Ll[2];
#pragma unroll
  for (int s = 0; s < 2; s++) {
    const float* rp = &Lf[(R + c) * LFS + 32 * s + 8 * q];
    const float4 v0 = *(const float4*)rp;
    const float4 v1 = *(const float4*)(rp + 4);
    float v[8] = {v0.x, v0.y, v0.z, v0.w, v1.x, v1.y, v1.z, v1.w};
#pragma unroll
    for (int j = 0; j < 8; j++) {
      const short hh = f2bs(v[j]);       const float r1 = v[j] - bs2f(hh);
      const short mm = f2bs(r1);         const float r2 = r1 - bs2f(mm);
      Lh[s][j] = hh; Lm[s][j] = mm; Ll[s][j] = f2bs(r2);
    }
  }
  // Wg2 fragment store: wave w builds tile tt=w&3; w<4 -> parts 0,1; w>=4 -> part 2
  {
    const int tt = w & 3;
    float v[8];
#pragma unroll
    for (int j = 0; j < 8; j++) v[j] = Wg2[(8 * q + j) * 64 + 16 * tt + c];
    if (w < 4) {
      s16x8 fh, fm;
#pragma unroll
      for (int j = 0; j < 8; j++) {
        const short hh = f2bs(v[j]);
        fh[j] = hh; fm[j] = f2bs(v[j] - bs2f(hh));
      }
      *(s16x8*)&WgF[((tt * 3 + 0) * 64 + l) * 8] = fh;
      *(s16x8*)&WgF[((tt * 3 + 1) * 64 + l) * 8] = fm;
    } else {
      s16x8 fl;
#pragma unroll
      for (int j = 0; j < 8; j++) {
        const short hh = f2bs(v[j]);     const float r1 = v[j] - bs2f(hh);
        const short mm = f2bs(r1);       const float r2 = r1 - bs2f(mm);
        fl[j] = f2bs(r2);
      }
      *(s16x8*)&WgF[((tt * 3 + 2) * 64 + l) * 8] = fl;
    }
  }
  // Ws2 frags (2-part) for this wave's two g-tiles, in registers
  s16x8 WsH[2], WsL[2];
#pragma unroll
  for (int i = 0; i < 2; i++) {
    const int g0 = 32 * h + 16 * i;
#pragma unroll
    for (int j = 0; j < 8; j++) {
      const float x = Ws2[(8 * q + j) * 64 + g0 + c];
      const short hh = f2bs(x);
      WsH[i][j] = hh; WsL[i][j] = f2bs(x - bs2f(hh));
    }
  }
  __syncthreads();

  // ================= init 3: layer-2 derived vectors =========================
  if (tid < 64) {
    const int g = tid;
    float a = 0.f, bb = 0.f, cc = 0.f, d = 0.f;
    for (int f = 0; f < 32; f++) {
      const float wg = Wg2[f * 64 + g], ws = Ws2[f * 64 + g];
      a += us1v[f] * wg; bb += cs1v[f] * wg;
      cc += us1v[f] * ws; d += cs1v[f] * ws;
    }
    u2gA[g] = a; c2gA[g] = bb; u2sA[g] = cc; cs2A[g] = d + bs2[g];
  }
  __syncthreads();

  // ================= init 4: per-lane constants (registers only) =============
  float u2g2[2], u2s2[2], cs22[2], c2c[2][4];
#pragma unroll
  for (int i = 0; i < 2; i++) {
    const int g = 32 * h + 16 * i + c;
    u2g2[i] = u2gA[g]; u2s2[i] = u2sA[g]; cs22[i] = cs2A[g];
    const float cg = c2gA[g], bg = bg2[g];
#pragma unroll
    for (int r = 0; r < 4; r++) c2c[i][r] = LsumS[R + 4 * q + r] * cg + bg;
  }
  // LIF-1 mapping (R17): thread (p,h,q,c) owns cells (rows R+4q+r, f2=16h+c);
  // cur uses the thread's own lx[r] (registers) -- no LxS, no alpha barrier.
  const int f2 = 16 * h + c;
  const float u1f = u1A[f2];
  float k1c[4];
  {
    const float cb = cb1A[f2], bg = bg1[f2];
#pragma unroll
    for (int r = 0; r < 4; r++) k1c[r] = LsumS[R + 4 * q + r] * cb + bg;
  }

  // ================= state registers =========================================
  float m1a[4], m1n[4], m1m[4];
#pragma unroll
  for (int j = 0; j < 4; j++) { m1a[j] = 0.f; m1n[j] = 0.f; m1m[j] = 0.f; }
  float m2a[2][4], m2n[2][4], m2m[2][4], mli[2][4], dpa[2][4];
#pragma unroll
  for (int i = 0; i < 2; i++)
#pragma unroll
    for (int r = 0; r < 4; r++) {
      m2a[i][r] = 0.f; m2n[i][r] = 0.f; m2m[i][r] = 0.f;
      mli[i][r] = 0.f; dpa[i][r] = 0.f;
    }

  const f32x4 fz = {0.f, 0.f, 0.f, 0.f};
  __syncthreads();   // Lf dead; UBUF becomes S1row/Mrow

  // ================= time loop: 2 barriers/step ==============================
  // Hazards (one barrier between reads and later writes suffices):
  //   B(t) S1row writes -> beta(t) -> C(t) S1row reads.
  //   C(t) S1row reads -> gamma(t) -> B(t+1) S1row writes.
  //   C(t) Mrow writes -> gamma(t) -> D(t) Mrow reads.
  //   D(t) Mrow reads -> beta(t+1) -> C(t+1) Mrow writes.
  for (int t = 0; t < 15; t++) {
    // ---- phase A: Lx = L@Xt via MFMA broadcast (all B-cols = Xt) ----
    f32x4 lx = fz;
#pragma unroll
    for (int s = 0; s < 2; s++) {
      const unsigned int* xw = &XtHL[t * 64 + 32 * s + 8 * q];
      const uint4 w0 = *(const uint4*)xw;
      const uint4 w1 = *(const uint4*)(xw + 4);
      unsigned int wv[8] = {w0.x, w0.y, w0.z, w0.w, w1.x, w1.y, w1.z, w1.w};
      s16x8 bh, bl;
#pragma unroll
      for (int j = 0; j < 8; j++) {
        bh[j] = (short)(wv[j] >> 16);
        bl[j] = (short)(wv[j] & 0xffff);
      }
      lx = MFMA16(Lh[s], bh, lx);
      lx = MFMA16(Lm[s], bh, lx);
      lx = MFMA16(Lh[s], bl, lx);
    }

    // ---- phase B: layer-1 LIF (register-only cur) -> S1row ----
#pragma unroll
    for (int r = 0; r < 4; r++) {
      const float cur = lx[r] * u1f + k1c[r];
      float ss = 0.f;
      LIF_STEP(m1a[r], 0.8f, 0.8f, cur, ss);
      LIF_STEP(m1n[r], 0.9f, 1.0f, cur, ss);
      LIF_STEP(m1m[r], 0.95f, 1.5f, cur, ss);
      S1row[(R + 4 * q + r) * RS + f2] = ss;
    }
    __syncthreads();   // beta

    // ---- phase C: M = L@S1 (3-part L), spk2d = S1@Ws2 (2-part W) ----
    f32x4 macc = fz;
#pragma unroll
    for (int s = 0; s < 2; s++) {
      s16x8 bS;
#pragma unroll
      for (int j = 0; j < 8; j++)
        bS[j] = f2bs(S1row[(32 * s + 8 * q + j) * RS + 16 * h + c]);
      macc = MFMA16(Lh[s], bS, macc);
      macc = MFMA16(Lm[s], bS, macc);
      macc = MFMA16(Ll[s], bS, macc);
    }
#pragma unroll
    for (int r = 0; r < 4; r++) Mrow[(R + 4 * q + r) * RS + 16 * h + c] = macc[r];

    f32x4 sacc[2];
    {
      const float* rp = &S1row[(R + c) * RS + 8 * q];
      const float4 v0 = *(const float4*)rp;
      const float4 v1 = *(const float4*)(rp + 4);
      const float v[8] = {v0.x, v0.y, v0.z, v0.w, v1.x, v1.y, v1.z, v1.w};
      s16x8 aS;
#pragma unroll
      for (int j = 0; j < 8; j++) aS[j] = f2bs(v[j]);
#pragma unroll
      for (int i = 0; i < 2; i++) {
        sacc[i] = MFMA16(aS, WsH[i], fz);
        sacc[i] = MFMA16(aS, WsL[i], sacc[i]);
      }
    }
    __syncthreads();   // gamma

    // ---- phase D: cur2 = M@Wg2 (6-term) + LIF-2 (all in registers) ----
    s16x8 aMh, aMm, aMl;
    {
      const float* rp = &Mrow[(R + c) * RS + 8 * q];
      const float4 v0 = *(const float4*)rp;
      const float4 v1 = *(const float4*)(rp + 4);
      const float v[8] = {v0.x, v0.y, v0.z, v0.w, v1.x, v1.y, v1.z, v1.w};
#pragma unroll
      for (int j = 0; j < 8; j++) {
        const short hh = f2bs(v[j]);     const float r1 = v[j] - bs2f(hh);
        const short mm = f2bs(r1);       const float r2 = r1 - bs2f(mm);
        aMh[j] = hh; aMm[j] = mm; aMl[j] = f2bs(r2);
      }
    }
    float xtn[4];
#pragma unroll
    for (int r = 0; r < 4; r++) xtn[r] = Xtf[t * 64 + R + 4 * q + r];

#pragma unroll
    for (int i = 0; i < 2; i++) {
      const int tt = 2 * h + i;
      const s16x8 bGh = *(const s16x8*)&WgF[((tt * 3 + 0) * 64 + l) * 8];
      const s16x8 bGm = *(const s16x8*)&WgF[((tt * 3 + 1) * 64 + l) * 8];
      const s16x8 bGl = *(const s16x8*)&WgF[((tt * 3 + 2) * 64 + l) * 8];
      f32x4 cacc = fz;
      cacc = MFMA16(aMh, bGh, cacc);
      cacc = MFMA16(aMh, bGm, cacc);
      cacc = MFMA16(aMm, bGh, cacc);
      cacc = MFMA16(aMh, bGl, cacc);
      cacc = MFMA16(aMm, bGm, cacc);
      cacc = MFMA16(aMl, bGh, cacc);
#pragma unroll
      for (int r = 0; r < 4; r++) {
        const float cur2 = cacc[r] + lx[r] * u2g2[i] + c2c[i][r];
        float ss = 0.f;
        LIF_STEP(m2a[i][r], 0.8f, 0.8f, cur2, ss);
        LIF_STEP(m2n[i][r], 0.9f, 1.0f, cur2, ss);
        LIF_STEP(m2m[i][r], 0.95f, 1.5f, cur2, ss);
        const float spk2 = ss + sacc[i][r] + xtn[r] * u2s2[i] + cs22[i];
        mli[i][r] = 0.9f * mli[i][r] + spk2;
      }
    }
    if (t < 5) {
#pragma unroll
      for (int i = 0; i < 2; i++)
#pragma unroll
        for (int r = 0; r < 4; r++) dpa[i][r] -= mli[i][r];
    } else if (t >= 10) {
#pragma unroll
      for (int i = 0; i < 2; i++)
#pragma unroll
        for (int r = 0; r < 4; r++) dpa[i][r] += mli[i][r];
    }
    // no end-of-step barrier (gamma(t) + beta(t+1) cover all hazards)
  }

  // ---- dp_feat = (sum_last5 - sum_first5)/5, packed split-bf16 ----
  unsigned int* dpb = dp_out + (size_t)b * 4096;
#pragma unroll
  for (int i = 0; i < 2; i++) {
    const int g = 32 * h + 16 * i + c;
#pragma unroll
    for (int r = 0; r < 4; r++) {
      const int n = R + 4 * q + r;
      const float v = dpa[i][r] * 0.2f;
      const short hh = f2bs(v);
      const short ll = f2bs(v - bs2f(hh));
      dpb[n * 64 + g] = ((unsigned int)(unsigned short)hh << 16) | (unsigned short)ll;
    }
  }
}

// Decoder v2 (R10 champion, verbatim): out = relu(dp @ W1 + b1) @ W2 + b2.
// 256 blocks x 512 threads (8 waves = 2/SIMD). Block = (16-batch group g) x
// (64-col half hb). Wave (tw, kh): col sub-tile tw, K-half kh (64 slices).
// Partial acc -> LDS Hp[2], one barrier, bias+relu+GEMM2. Second GEMM:
// 64-col partial per block via f32 atomicAdd (2 commutative contributions
// per element; out zeroed by hipMemsetAsync; each block adds b2/2).

#define DEC_STEP(S, CA0, CA1)                                          \
  {                                                                    \
    const unsigned int av[8] = {(CA0).x, (CA0).y, (CA0).z, (CA0).w,    \
                                (CA1).x, (CA1).y, (CA1).z, (CA1).w};   \
    s16x8 Ah, Al, Bh, Bl;                                              \
    _Pragma("unroll")                                                  \
    for (int j = 0; j < 8; j++) {                                      \
      Ah[j] = (short)(av[j] >> 16);                                    \
      Al[j] = (short)(av[j] & 0xffff);                                 \
      const float x = bcol2[(32 * (S) + j) * 128];                     \
      const short hh = f2bs(x);                                        \
      Bh[j] = hh; Bl[j] = f2bs(x - bs2f(hh));                          \
    }                                                                  \
    acc = MFMA16(Ah, Bh, acc);                                         \
    acc = MFMA16(Al, Bh, acc);                                         \
    acc = MFMA16(Ah, Bl, acc);                                         \
  }

#define DEC_SLOT(S, BUF, NXT)                                          \
  {                                                                    \
    const uint4 c0 = BUF[0], c1 = BUF[1];                              \
    if ((NXT) < 64) {                                                  \
      BUF[0] = *(const uint4*)(arow2 + 32 * (NXT));                    \
      BUF[1] = *(const uint4*)(arow2 + 32 * (NXT) + 4);                \
    }                                                                  \
    DEC_STEP(S, c0, c1);                                               \
  }

__global__ __launch_bounds__(512, 2)
void hrsnn_decoder(const unsigned int* __restrict__ dpq, const float* __restrict__ W1,
                   const float* __restrict__ b1, const float* __restrict__ W2,
                   const float* __restrict__ b2, float* __restrict__ out)
{
  __shared__ __align__(16) float Hp[2][16][68];   // partial acc per K-half
  const int tid = threadIdx.x;
  const int l = tid & 63, w = tid >> 6;
  const int tw = w & 3, kh = w >> 2;           // col sub-tile / K half
  const int g  = blockIdx.x >> 1;              // batch group (16 rows)
  const int hb = blockIdx.x & 1;               // col half (64 of 128)
  const int q = l >> 4, c = l & 15;
  const int col = 64 * hb + 16 * tw + c;

  const unsigned int* arow2 = dpq + (size_t)(g * 16 + c) * 4096 + 2048 * kh + 8 * q;
  const float* bcol2 = W1 + (size_t)(2048 * kh + 8 * q) * 128 + col;

  f32x4 acc = {0.f, 0.f, 0.f, 0.f};
  uint4 A0[2], A1[2], A2[2], A3[2];
  A0[0] = *(const uint4*)(arow2);       A0[1] = *(const uint4*)(arow2 + 4);
  A1[0] = *(const uint4*)(arow2 + 32);  A1[1] = *(const uint4*)(arow2 + 36);
  A2[0] = *(const uint4*)(arow2 + 64);  A2[1] = *(const uint4*)(arow2 + 68);
  A3[0] = *(const uint4*)(arow2 + 96);  A3[1] = *(const uint4*)(arow2 + 100);
  for (int sl = 0; sl < 64; sl += 4) {
    DEC_SLOT(sl,     A0, sl + 4);
    DEC_SLOT(sl + 1, A1, sl + 5);
    DEC_SLOT(sl + 2, A2, sl + 6);
    DEC_SLOT(sl + 3, A3, sl + 7);
  }

#pragma unroll
  for (int r = 0; r < 4; r++) Hp[kh][4 * q + r][16 * tw + c] = acc[r];
  __syncthreads();

  if (tid < 64) {
    const int i = tid >> 2, o = tid & 3;
    float s = 0.5f * b2[o];
    const float* b1h = b1 + 64 * hb;
    const float* w2 = W2 + (64 * hb) * 4 + o;
    for (int k = 0; k < 64; k++) {
      float hv = Hp[0][i][k] + Hp[1][i][k] + b1h[k];
      hv = hv > 0.f ? hv : 0.f;
      s += hv * w2[k * 4];
    }
    atomicAdd(&out[(size_t)(g * 16 + i) * 4 + o], s);
  }
}

extern "C" void kernel_launch(void* const* d_in, const int* in_sizes, int n_in,
                              void* d_out, int out_size, void* d_ws, size_t ws_size,
                              hipStream_t stream)
{
  const float* Lg  = (const float*)d_in[0];
  const float* Xg  = (const float*)d_in[1];
  const float* Wp  = (const float*)d_in[2];
  const float* bp  = (const float*)d_in[3];
  const float* Wg1 = (const float*)d_in[4];
  const float* bg1 = (const float*)d_in[5];
  const float* Ws1 = (const float*)d_in[6];
  const float* bs1 = (const float*)d_in[7];
  const float* Wg2 = (const float*)d_in[8];
  const float* bg2 = (const float*)d_in[9];
  const float* Ws2 = (const float*)d_in[10];
  const float* bs2 = (const float*)d_in[11];
  const float* W1  = (const float*)d_in[12];
  const float* b1  = (const float*)d_in[13];
  const float* W2  = (const float*)d_in[14];
  const float* b2  = (const float*)d_in[15];

  unsigned int* dpq = (unsigned int*)d_ws;  // 2048*4096 packed uint = 32 MB
  float* out = (float*)d_out;               // [2048, 4] f32

  hipLaunchKernelGGL(hrsnn_main, dim3(2048), dim3(512), 0, stream,
                     Lg, Xg, Wp, bp, Wg1, bg1, Ws1, bs1, Wg2, bg2, Ws2, bs2, dpq);
  hipMemsetAsync(out, 0, (size_t)2048 * 4 * sizeof(float), stream);
  hipLaunchKernelGGL(hrsnn_decoder, dim3(256), dim3(512), 0, stream,
                     dpq, W1, b1, W2, b2, out);
}

// Round 14
// 422.945 us; speedup vs baseline: 1.8631x; 1.0119x over previous
//
#include <hip/hip_runtime.h>
#include <hip/hip_bf16.h>

// RiemannianGraph_HRSNN, MFMA version. B=2048, T=15, N=64. All I/O f32.
// R19: R18 RESUBMIT (discriminator). R18 core-dumped with zero diagnostic
// signal (SIGABRT in pytest, no absmax, no fault address in visible log).
// Full re-audit of the R17->R18 diff found no defect: LxAll write/read
// bounds <=1023/1024; XtHL uint4 reads <=959/960 and 16B-aligned; init-2b
// reads XtHL after init-1's barrier and LxAll is re-read only after >=2
// barriers; the loop's 2-barrier hazard structure is R17's (which passed);
// no new global accesses. Session has documented infra noise (R14 30ms
// dispatch outlier, multi-100s push stalls). Deterministic recompile makes
// this a clean discriminator: crash again => real, revert to R17 (427.96us
// champion) permanently; pass => hoist banked (~20us).
//
// R18: PHASE-A HOIST. Phase A ran 6 dependent MFMAs + ~40 unpack VALU per
// step (90 serial MFMAs total) computing Lx(t)=L@Xt; but Xt for ALL t is
// known at init, so LxAll[n][t] is computed in ONE batched MFMA pass at
// init (B cols = time-steps: B[k][col=c]=XtHL[c*64+k], col 15 unused) and
// the loop reads lxr[r]=LxAll[(R+4q+r)*16+t]. Bit-identity: MFMA output
// col t depends only on B col t, and the accumulation chain (s0: Lh*bh,
// Lm*bh, Lh*bl; s1: same) is textually identical to R17's -> identical lx
// values; cur/cur2 expression forms unchanged -> same spikes.
// Loop: 2 barriers/step, hazards unchanged. LDS 44.3KB, 2 blocks/CU.
// Decoder: R10 verbatim.
//
// Main-kernel math (unchanged from R4):
//   L 3-part x S1(exact)            -> 2^-27
//   M 3-part x Wg2 3-part (6 terms) -> ~2^-24
//   S1(exact) x Ws2 2-part          -> 2^-18 (no threshold downstream)
//   L 3-part x Xt 2-part (3 terms)  -> ~2^-17
// MFMA layouts: A[row=lane&15][k=8*(lane>>4)+j], B[k=8q+j][col=lane&15],
// C/D[row=4*(lane>>4)+reg][col=lane&15].

typedef __attribute__((ext_vector_type(8))) short s16x8;
typedef __attribute__((ext_vector_type(4))) float f32x4;
#define MFMA16(a, b, c) __builtin_amdgcn_mfma_f32_16x16x32_bf16(a, b, c, 0, 0, 0)

__device__ __forceinline__ short f2bs(float x) {
  union { __hip_bfloat16 h; short s; } u; u.h = __float2bfloat16(x); return u.s;
}
__device__ __forceinline__ float bs2f(short s) {
  union { short s; __hip_bfloat16 h; } u; u.s = s; return __bfloat162float(u.h);
}

#define LIF_STEP(mem, beta, thr, cur, spksum)                \
  {                                                          \
    float r_ = ((mem) > (thr)) ? (thr) : 0.0f;               \
    (mem) = (beta) * (mem) + (cur) - r_;                     \
    (spksum) += (((mem) - (thr)) > 0.0f) ? 1.0f : 0.0f;      \
  }

#define LFS 68      // Lf row stride (f32 words)
#define RS  36      // S1row / Mrow row stride

__global__ __launch_bounds__(512, 2)
void hrsnn_main(const float* __restrict__ Lg,  const float* __restrict__ Xg,
                const float* __restrict__ Wp,  const float* __restrict__ bp,
                const float* __restrict__ Wg1, const float* __restrict__ bg1,
                const float* __restrict__ Ws1, const float* __restrict__ bs1,
                const float* __restrict__ Wg2, const float* __restrict__ bg2,
                const float* __restrict__ Ws2, const float* __restrict__ bs2,
                unsigned int* __restrict__ dp_out)
{
  // UBUF: union of Lf[64][68] (init only, 4352) with S1row[64][36]+Mrow[64][36]
  __shared__ __align__(16) float UBUF[4608];
  float* const Lf    = UBUF;          // init only
  float* const S1row = UBUF;          // [64][RS]
  float* const Mrow  = UBUF + 2304;   // [64][RS]
  __shared__ __align__(16) short WgF[4 * 3 * 64 * 8];   // Wg2 frags [tile][part][lane][8]
  __shared__ __align__(16) unsigned int XtHL[960];      // packed (hi<<16|lo) bf16 of Xt
  __shared__ __align__(16) float Xtf[960];
  __shared__ __align__(16) float LxAll[1024];           // Lx[n][t] precomputed, [64][16]
  __shared__ float LsumS[64];
  __shared__ float u1A[32], cb1A[32], us1v[32], cs1v[32];
  __shared__ float u2gA[64], c2gA[64], u2sA[64], cs2A[64];

  const int tid = threadIdx.x;
  const int b = blockIdx.x;
  const int l = tid & 63, w = tid >> 6;
  const int p = w >> 1, h = w & 1;          // row-stripe / col-half
  const int q = l >> 4, c = l & 15;
  const int R = 16 * p;

  // ================= init 1: stage Lf, Xt (split), small weight folds ========
  const float* Lb = Lg + (size_t)b * 4096;
#pragma unroll
  for (int k = 0; k < 2; k++) {
    const int i4 = tid + 512 * k;                 // float4 index in [0,1024)
    const float4 v = *(const float4*)&Lb[i4 * 4];
    *(float4*)&Lf[(i4 >> 4) * LFS + (i4 & 15) * 4] = v;
  }
  const float* Xb = Xg + (size_t)b * 960;
  for (int i = tid; i < 960; i += 512) {
    const float x = Xb[i];
    const short hs = f2bs(x);
    const short ls = f2bs(x - bs2f(hs));
    XtHL[i] = ((unsigned int)(unsigned short)hs << 16) | (unsigned short)ls;
    Xtf[i] = x;
  }
  if (tid < 32) {
    const int f = tid;
    float a = 0.f, bb = 0.f, cc = 0.f, d = 0.f;
    for (int k = 0; k < 16; k++) {
      const float wp = Wp[k], bpv = bp[k];
      const float wg = Wg1[k * 32 + f], ws = Ws1[k * 32 + f];
      a += wp * wg; bb += bpv * wg;
      cc += wp * ws; d += bpv * ws;
    }
    u1A[f] = a; cb1A[f] = bb;
    us1v[f] = cc; cs1v[f] = d + bs1[f];
  }
  __syncthreads();

  // ================= init 2: Lsum, L A-frags, WgF, Ws2 frags ================
  {
    const int n = tid >> 3, o = tid & 7;
    const float4 a4 = *(const float4*)&Lf[n * LFS + 8 * o];
    const float4 b4 = *(const float4*)&Lf[n * LFS + 8 * o + 4];
    float ps = a4.x + a4.y + a4.z + a4.w + b4.x + b4.y + b4.z + b4.w;
    ps += __shfl_xor(ps, 1, 64);
    ps += __shfl_xor(ps, 2, 64);
    ps += __shfl_xor(ps, 4, 64);
    if (o == 0) LsumS[n] = ps;
  }
  // L A-frags: 3 parts x 2 K-slices (K=64)
  s16x8 Lh[2], Lm[2], Ll[2];
#pragma unroll
  for (int s = 0; s < 2; s++) {
    const float* rp = &Lf[(R + c) * LFS + 32 * s + 8 * q];
    const float4 v0 = *(const float4*)rp;
    const float4 v1 = *(const float4*)(rp + 4);
    float v[8] = {v0.x, v0.y, v0.z, v0.w, v1.x, v1.y, v1.z, v1.w};
#pragma unroll
    for (int j = 0; j < 8; j++) {
      const short hh = f2bs(v[j]);       const float r1 = v[j] - bs2f(hh);
      const short mm = f2bs(r1);         const float r2 = r1 - bs2f(mm);
      Lh[s][j] = hh; Lm[s][j] = mm; Ll[s][j] = f2bs(r2);
    }
  }
  // Wg2 fragment store: wave w builds tile tt=w&3; w<4 -> parts 0,1; w>=4 -> part 2
  {
    const int tt = w & 3;
    float v[8];
#pragma unroll
    for (int j = 0; j < 8; j++) v[j] = Wg2[(8 * q + j) * 64 + 16 * tt + c];
    if (w < 4) {
      s16x8 fh, fm;
#pragma unroll
      for (int j = 0; j < 8; j++) {
        const short hh = f2bs(v[j]);
        fh[j] = hh; fm[j] = f2bs(v[j] - bs2f(hh));
      }
      *(s16x8*)&WgF[((tt * 3 + 0) * 64 + l) * 8] = fh;
      *(s16x8*)&WgF[((tt * 3 + 1) * 64 + l) * 8] = fm;
    } else {
      s16x8 fl;
#pragma unroll
      for (int j = 0; j < 8; j++) {
        const short hh = f2bs(v[j]);     const float r1 = v[j] - bs2f(hh);
        const short mm = f2bs(r1);       const float r2 = r1 - bs2f(mm);
        fl[j] = f2bs(r2);
      }
      *(s16x8*)&WgF[((tt * 3 + 2) * 64 + l) * 8] = fl;
    }
  }
  // Ws2 frags (2-part) for this wave's two g-tiles, in registers
  s16x8 WsH[2], WsL[2];
#pragma unroll
  for (int i = 0; i < 2; i++) {
    const int g0 = 32 * h + 16 * i;
#pragma unroll
    for (int j = 0; j < 8; j++) {
      const float x = Ws2[(8 * q + j) * 64 + g0 + c];
      const short hh = f2bs(x);
      WsH[i][j] = hh; WsL[i][j] = f2bs(x - bs2f(hh));
    }
  }

  // ---- init 2b: LxAll[n][t] = (L @ Xt^T)[n][t] via ONE batched MFMA pass ----
  // B operand: col c = time-step (c<15; col 15 = copy of t=14, never read).
  // Lane c reads its own column's Xt packed values; accumulation chain is
  // textually identical to R17's per-step phase A -> column t is
  // bit-identical to the per-step lx. h==0 stores.
  {
    const f32x4 fz0 = {0.f, 0.f, 0.f, 0.f};
    f32x4 lxall = fz0;
    const int tc = c < 15 ? c : 14;    // clamp: col 15 = copy of t=14, unused
#pragma unroll
    for (int s = 0; s < 2; s++) {
      const unsigned int* xw = &XtHL[tc * 64 + 32 * s + 8 * q];
      const uint4 w0 = *(const uint4*)xw;
      const uint4 w1 = *(const uint4*)(xw + 4);
      unsigned int wv[8] = {w0.x, w0.y, w0.z, w0.w, w1.x, w1.y, w1.z, w1.w};
      s16x8 bh, bl;
#pragma unroll
      for (int j = 0; j < 8; j++) {
        bh[j] = (short)(wv[j] >> 16);
        bl[j] = (short)(wv[j] & 0xffff);
      }
      lxall = MFMA16(Lh[s], bh, lxall);
      lxall = MFMA16(Lm[s], bh, lxall);
      lxall = MFMA16(Lh[s], bl, lxall);
    }
    if (h == 0) {
#pragma unroll
      for (int r = 0; r < 4; r++) LxAll[(R + 4 * q + r) * 16 + c] = lxall[r];
    }
  }
  __syncthreads();

  // ================= init 3: layer-2 derived vectors =========================
  if (tid < 64) {
    const int g = tid;
    float a = 0.f, bb = 0.f, cc = 0.f, d = 0.f;
    for (int f = 0; f < 32; f++) {
      const float wg = Wg2[f * 64 + g], ws = Ws2[f * 64 + g];
      a += us1v[f] * wg; bb += cs1v[f] * wg;
      cc += us1v[f] * ws; d += cs1v[f] * ws;
    }
    u2gA[g] = a; c2gA[g] = bb; u2sA[g] = cc; cs2A[g] = d + bs2[g];
  }
  __syncthreads();

  // ================= init 4: per-lane constants (registers only) =============
  float u2g2[2], u2s2[2], cs22[2], c2c[2][4];
#pragma unroll
  for (int i = 0; i < 2; i++) {
    const int g = 32 * h + 16 * i + c;
    u2g2[i] = u2gA[g]; u2s2[i] = u2sA[g]; cs22[i] = cs2A[g];
    const float cg = c2gA[g], bg = bg2[g];
#pragma unroll
    for (int r = 0; r < 4; r++) c2c[i][r] = LsumS[R + 4 * q + r] * cg + bg;
  }
  // LIF-1 mapping (R17): thread (p,h,q,c) owns cells (rows R+4q+r, f2=16h+c)
  const int f2 = 16 * h + c;
  const float u1f = u1A[f2];
  float k1c[4];
  {
    const float cb = cb1A[f2], bg = bg1[f2];
#pragma unroll
    for (int r = 0; r < 4; r++) k1c[r] = LsumS[R + 4 * q + r] * cb + bg;
  }

  // ================= state registers =========================================
  float m1a[4], m1n[4], m1m[4];
#pragma unroll
  for (int j = 0; j < 4; j++) { m1a[j] = 0.f; m1n[j] = 0.f; m1m[j] = 0.f; }
  float m2a[2][4], m2n[2][4], m2m[2][4], mli[2][4], dpa[2][4];
#pragma unroll
  for (int i = 0; i < 2; i++)
#pragma unroll
    for (int r = 0; r < 4; r++) {
      m2a[i][r] = 0.f; m2n[i][r] = 0.f; m2m[i][r] = 0.f;
      mli[i][r] = 0.f; dpa[i][r] = 0.f;
    }

  const f32x4 fz = {0.f, 0.f, 0.f, 0.f};
  __syncthreads();   // Lf dead; UBUF becomes S1row/Mrow

  // ================= time loop: 2 barriers/step ==============================
  // Hazards (one barrier between reads and later writes suffices):
  //   B(t) S1row writes -> beta(t) -> C(t) S1row reads.
  //   C(t) S1row reads -> gamma(t) -> B(t+1) S1row writes.
  //   C(t) Mrow writes -> gamma(t) -> D(t) Mrow reads.
  //   D(t) Mrow reads -> beta(t+1) -> C(t+1) Mrow writes.
  // LxAll is read-only during the loop.
  for (int t = 0; t < 15; t++) {
    // ---- lx for this step: 4 broadcast LDS reads (phase A hoisted) ----
    float lxr[4];
#pragma unroll
    for (int r = 0; r < 4; r++) lxr[r] = LxAll[(R + 4 * q + r) * 16 + t];

    // ---- phase B: layer-1 LIF (register-only cur) -> S1row ----
#pragma unroll
    for (int r = 0; r < 4; r++) {
      const float cur = lxr[r] * u1f + k1c[r];
      float ss = 0.f;
      LIF_STEP(m1a[r], 0.8f, 0.8f, cur, ss);
      LIF_STEP(m1n[r], 0.9f, 1.0f, cur, ss);
      LIF_STEP(m1m[r], 0.95f, 1.5f, cur, ss);
      S1row[(R + 4 * q + r) * RS + f2] = ss;
    }
    __syncthreads();   // beta

    // ---- phase C: M = L@S1 (3-part L), spk2d = S1@Ws2 (2-part W) ----
    f32x4 macc = fz;
#pragma unroll
    for (int s = 0; s < 2; s++) {
      s16x8 bS;
#pragma unroll
      for (int j = 0; j < 8; j++)
        bS[j] = f2bs(S1row[(32 * s + 8 * q + j) * RS + 16 * h + c]);
      macc = MFMA16(Lh[s], bS, macc);
      macc = MFMA16(Lm[s], bS, macc);
      macc = MFMA16(Ll[s], bS, macc);
    }
#pragma unroll
    for (int r = 0; r < 4; r++) Mrow[(R + 4 * q + r) * RS + 16 * h + c] = macc[r];

    f32x4 sacc[2];
    {
      const float* rp = &S1row[(R + c) * RS + 8 * q];
      const float4 v0 = *(const float4*)rp;
      const float4 v1 = *(const float4*)(rp + 4);
      const float v[8] = {v0.x, v0.y, v0.z, v0.w, v1.x, v1.y, v1.z, v1.w};
      s16x8 aS;
#pragma unroll
      for (int j = 0; j < 8; j++) aS[j] = f2bs(v[j]);
#pragma unroll
      for (int i = 0; i < 2; i++) {
        sacc[i] = MFMA16(aS, WsH[i], fz);
        sacc[i] = MFMA16(aS, WsL[i], sacc[i]);
      }
    }
    __syncthreads();   // gamma

    // ---- phase D: cur2 = M@Wg2 (6-term) + LIF-2 (all in registers) ----
    s16x8 aMh, aMm, aMl;
    {
      const float* rp = &Mrow[(R + c) * RS + 8 * q];
      const float4 v0 = *(const float4*)rp;
      const float4 v1 = *(const float4*)(rp + 4);
      const float v[8] = {v0.x, v0.y, v0.z, v0.w, v1.x, v1.y, v1.z, v1.w};
#pragma unroll
      for (int j = 0; j < 8; j++) {
        const short hh = f2bs(v[j]);     const float r1 = v[j] - bs2f(hh);
        const short mm = f2bs(r1);       const float r2 = r1 - bs2f(mm);
        aMh[j] = hh; aMm[j] = mm; aMl[j] = f2bs(r2);
      }
    }
    float xtn[4];
#pragma unroll
    for (int r = 0; r < 4; r++) xtn[r] = Xtf[t * 64 + R + 4 * q + r];

#pragma unroll
    for (int i = 0; i < 2; i++) {
      const int tt = 2 * h + i;
      const s16x8 bGh = *(const s16x8*)&WgF[((tt * 3 + 0) * 64 + l) * 8];
      const s16x8 bGm = *(const s16x8*)&WgF[((tt * 3 + 1) * 64 + l) * 8];
      const s16x8 bGl = *(const s16x8*)&WgF[((tt * 3 + 2) * 64 + l) * 8];
      f32x4 cacc = fz;
      cacc = MFMA16(aMh, bGh, cacc);
      cacc = MFMA16(aMh, bGm, cacc);
      cacc = MFMA16(aMm, bGh, cacc);
      cacc = MFMA16(aMh, bGl, cacc);
      cacc = MFMA16(aMm, bGm, cacc);
      cacc = MFMA16(aMl, bGh, cacc);
#pragma unroll
      for (int r = 0; r < 4; r++) {
        const float cur2 = cacc[r] + lxr[r] * u2g2[i] + c2c[i][r];
        float ss = 0.f;
        LIF_STEP(m2a[i][r], 0.8f, 0.8f, cur2, ss);
        LIF_STEP(m2n[i][r], 0.9f, 1.0f, cur2, ss);
        LIF_STEP(m2m[i][r], 0.95f, 1.5f, cur2, ss);
        const float spk2 = ss + sacc[i][r] + xtn[r] * u2s2[i] + cs22[i];
        mli[i][r] = 0.9f * mli[i][r] + spk2;
      }
    }
    if (t < 5) {
#pragma unroll
      for (int i = 0; i < 2; i++)
#pragma unroll
        for (int r = 0; r < 4; r++) dpa[i][r] -= mli[i][r];
    } else if (t >= 10) {
#pragma unroll
      for (int i = 0; i < 2; i++)
#pragma unroll
        for (int r = 0; r < 4; r++) dpa[i][r] += mli[i][r];
    }
    // no end-of-step barrier (gamma(t) + beta(t+1) cover all hazards)
  }

  // ---- dp_feat = (sum_last5 - sum_first5)/5, packed split-bf16 ----
  unsigned int* dpb = dp_out + (size_t)b * 4096;
#pragma unroll
  for (int i = 0; i < 2; i++) {
    const int g = 32 * h + 16 * i + c;
#pragma unroll
    for (int r = 0; r < 4; r++) {
      const int n = R + 4 * q + r;
      const float v = dpa[i][r] * 0.2f;
      const short hh = f2bs(v);
      const short ll = f2bs(v - bs2f(hh));
      dpb[n * 64 + g] = ((unsigned int)(unsigned short)hh << 16) | (unsigned short)ll;
    }
  }
}

// Decoder v2 (R10 champion, verbatim): out = relu(dp @ W1 + b1) @ W2 + b2.
// 256 blocks x 512 threads (8 waves = 2/SIMD). Block = (16-batch group g) x
// (64-col half hb). Wave (tw, kh): col sub-tile tw, K-half kh (64 slices).
// Partial acc -> LDS Hp[2], one barrier, bias+relu+GEMM2. Second GEMM:
// 64-col partial per block via f32 atomicAdd (2 commutative contributions
// per element; out zeroed by hipMemsetAsync; each block adds b2/2).

#define DEC_STEP(S, CA0, CA1)                                          \
  {                                                                    \
    const unsigned int av[8] = {(CA0).x, (CA0).y, (CA0).z, (CA0).w,    \
                                (CA1).x, (CA1).y, (CA1).z, (CA1).w};   \
    s16x8 Ah, Al, Bh, Bl;                                              \
    _Pragma("unroll")                                                  \
    for (int j = 0; j < 8; j++) {                                      \
      Ah[j] = (short)(av[j] >> 16);                                    \
      Al[j] = (short)(av[j] & 0xffff);                                 \
      const float x = bcol2[(32 * (S) + j) * 128];                     \
      const short hh = f2bs(x);                                        \
      Bh[j] = hh; Bl[j] = f2bs(x - bs2f(hh));                          \
    }                                                                  \
    acc = MFMA16(Ah, Bh, acc);                                         \
    acc = MFMA16(Al, Bh, acc);                                         \
    acc = MFMA16(Ah, Bl, acc);                                         \
  }

#define DEC_SLOT(S, BUF, NXT)                                          \
  {                                                                    \
    const uint4 c0 = BUF[0], c1 = BUF[1];                              \
    if ((NXT) < 64) {                                                  \
      BUF[0] = *(const uint4*)(arow2 + 32 * (NXT));                    \
      BUF[1] = *(const uint4*)(arow2 + 32 * (NXT) + 4);                \
    }                                                                  \
    DEC_STEP(S, c0, c1);                                               \
  }

__global__ __launch_bounds__(512, 2)
void hrsnn_decoder(const unsigned int* __restrict__ dpq, const float* __restrict__ W1,
                   const float* __restrict__ b1, const float* __restrict__ W2,
                   const float* __restrict__ b2, float* __restrict__ out)
{
  __shared__ __align__(16) float Hp[2][16][68];   // partial acc per K-half
  const int tid = threadIdx.x;
  const int l = tid & 63, w = tid >> 6;
  const int tw = w & 3, kh = w >> 2;           // col sub-tile / K half
  const int g  = blockIdx.x >> 1;              // batch group (16 rows)
  const int hb = blockIdx.x & 1;               // col half (64 of 128)
  const int q = l >> 4, c = l & 15;
  const int col = 64 * hb + 16 * tw + c;

  const unsigned int* arow2 = dpq + (size_t)(g * 16 + c) * 4096 + 2048 * kh + 8 * q;
  const float* bcol2 = W1 + (size_t)(2048 * kh + 8 * q) * 128 + col;

  f32x4 acc = {0.f, 0.f, 0.f, 0.f};
  uint4 A0[2], A1[2], A2[2], A3[2];
  A0[0] = *(const uint4*)(arow2);       A0[1] = *(const uint4*)(arow2 + 4);
  A1[0] = *(const uint4*)(arow2 + 32);  A1[1] = *(const uint4*)(arow2 + 36);
  A2[0] = *(const uint4*)(arow2 + 64);  A2[1] = *(const uint4*)(arow2 + 68);
  A3[0] = *(const uint4*)(arow2 + 96);  A3[1] = *(const uint4*)(arow2 + 100);
  for (int sl = 0; sl < 64; sl += 4) {
    DEC_SLOT(sl,     A0, sl + 4);
    DEC_SLOT(sl + 1, A1, sl + 5);
    DEC_SLOT(sl + 2, A2, sl + 6);
    DEC_SLOT(sl + 3, A3, sl + 7);
  }

#pragma unroll
  for (int r = 0; r < 4; r++) Hp[kh][4 * q + r][16 * tw + c] = acc[r];
  __syncthreads();

  if (tid < 64) {
    const int i = tid >> 2, o = tid & 3;
    float s = 0.5f * b2[o];
    const float* b1h = b1 + 64 * hb;
    const float* w2 = W2 + (64 * hb) * 4 + o;
    for (int k = 0; k < 64; k++) {
      float hv = Hp[0][i][k] + Hp[1][i][k] + b1h[k];
      hv = hv > 0.f ? hv : 0.f;
      s += hv * w2[k * 4];
    }
    atomicAdd(&out[(size_t)(g * 16 + i) * 4 + o], s);
  }
}

extern "C" void kernel_launch(void* const* d_in, const int* in_sizes, int n_in,
                              void* d_out, int out_size, void* d_ws, size_t ws_size,
                              hipStream_t stream)
{
  const float* Lg  = (const float*)d_in[0];
  const float* Xg  = (const float*)d_in[1];
  const float* Wp  = (const float*)d_in[2];
  const float* bp  = (const float*)d_in[3];
  const float* Wg1 = (const float*)d_in[4];
  const float* bg1 = (const float*)d_in[5];
  const float* Ws1 = (const float*)d_in[6];
  const float* bs1 = (const float*)d_in[7];
  const float* Wg2 = (const float*)d_in[8];
  const float* bg2 = (const float*)d_in[9];
  const float* Ws2 = (const float*)d_in[10];
  const float* bs2 = (const float*)d_in[11];
  const float* W1  = (const float*)d_in[12];
  const float* b1  = (const float*)d_in[13];
  const float* W2  = (const float*)d_in[14];
  const float* b2  = (const float*)d_in[15];

  unsigned int* dpq = (unsigned int*)d_ws;  // 2048*4096 packed uint = 32 MB
  float* out = (float*)d_out;               // [2048, 4] f32

  hipLaunchKernelGGL(hrsnn_main, dim3(2048), dim3(512), 0, stream,
                     Lg, Xg, Wp, bp, Wg1, bg1, Ws1, bs1, Wg2, bg2, Ws2, bs2, dpq);
  hipMemsetAsync(out, 0, (size_t)2048 * 4 * sizeof(float), stream);
  hipLaunchKernelGGL(hrsnn_decoder, dim3(256), dim3(512), 0, stream,
                     dpq, W1, b1, W2, b2, out);
}

// Round 15
// 410.331 us; speedup vs baseline: 1.9204x; 1.0307x over previous
//
#include <hip/hip_runtime.h>
#include <hip/hip_bf16.h>

// RiemannianGraph_HRSNN, MFMA version. B=2048, T=15, N=64. All I/O f32.
// R20: two bit-identical micro-fixes to the serial chain (R19 = 422.94us
// champion; main 321us, latency-bound, MfmaUtil 11.7 / VALU 48.7 / Occ 23).
// (1) S1 stored as bf16 in LDS: spike sums are in {0,1,2,3} (bf16-exact)
//     and every consumer applies f2bs immediately -- writing f2bs(ss) once
//     (4 f2bs added in B) deletes ~24 f2bs/step from the chain (bS: 16
//     read+convert -> 16 u16 reads; aS: 2xfloat4+8 f2bs -> 8 short reads).
//     f2bs commutes with the store -> MFMA operands bit-identical. Bonus:
//     bS column reads as shorts are 2-way-conflict (free) vs 4-way as f32.
// (2) LxAll padded to stride 17: R19's [64][16] put all four q-groups in
//     one bank (64 words = 0 mod 32, +4e6 conflicts); stride 17 -> 68 = 4
//     mod 32, conflict-free.
// Same (512,2), same R17 2-barrier hazard structure, same expression forms
// (correctness class of R15/R17/R19: every (512,2) structural edit kept
// absmax 0.375). Decoder: R10 verbatim.
//
// Main-kernel math (unchanged from R4):
//   L 3-part x S1(exact)            -> 2^-27
//   M 3-part x Wg2 3-part (6 terms) -> ~2^-24
//   S1(exact) x Ws2 2-part          -> 2^-18 (no threshold downstream)
//   L 3-part x Xt 2-part (3 terms)  -> ~2^-17
// MFMA layouts: A[row=lane&15][k=8*(lane>>4)+j], B[k=8q+j][col=lane&15],
// C/D[row=4*(lane>>4)+reg][col=lane&15].

typedef __attribute__((ext_vector_type(8))) short s16x8;
typedef __attribute__((ext_vector_type(4))) float f32x4;
#define MFMA16(a, b, c) __builtin_amdgcn_mfma_f32_16x16x32_bf16(a, b, c, 0, 0, 0)

__device__ __forceinline__ short f2bs(float x) {
  union { __hip_bfloat16 h; short s; } u; u.h = __float2bfloat16(x); return u.s;
}
__device__ __forceinline__ float bs2f(short s) {
  union { short s; __hip_bfloat16 h; } u; u.s = s; return __bfloat162float(u.h);
}

#define LIF_STEP(mem, beta, thr, cur, spksum)                \
  {                                                          \
    float r_ = ((mem) > (thr)) ? (thr) : 0.0f;               \
    (mem) = (beta) * (mem) + (cur) - r_;                     \
    (spksum) += (((mem) - (thr)) > 0.0f) ? 1.0f : 0.0f;      \
  }

#define LFS 68      // Lf row stride (f32 words)
#define RS  36      // Mrow row stride (f32 words); S1b row stride (shorts)

__global__ __launch_bounds__(512, 2)
void hrsnn_main(const float* __restrict__ Lg,  const float* __restrict__ Xg,
                const float* __restrict__ Wp,  const float* __restrict__ bp,
                const float* __restrict__ Wg1, const float* __restrict__ bg1,
                const float* __restrict__ Ws1, const float* __restrict__ bs1,
                const float* __restrict__ Wg2, const float* __restrict__ bg2,
                const float* __restrict__ Ws2, const float* __restrict__ bs2,
                unsigned int* __restrict__ dp_out)
{
  // UBUF: union of Lf[64][68] (init only, 4352 f32) with
  //   S1b[64][36] shorts (first 1152 f32) + Mrow[64][36] f32 (at +2304).
  __shared__ __align__(16) float UBUF[4608];
  float* const Lf    = UBUF;               // init only
  short* const S1b   = (short*)UBUF;       // [64][RS] shorts (spike sums, bf16)
  float* const Mrow  = UBUF + 2304;        // [64][RS] f32
  __shared__ __align__(16) short WgF[4 * 3 * 64 * 8];   // Wg2 frags [tile][part][lane][8]
  __shared__ __align__(16) unsigned int XtHL[960];      // packed (hi<<16|lo) bf16 of Xt
  __shared__ __align__(16) float Xtf[960];
  __shared__ __align__(16) float LxAll[1088];           // Lx[n][t], stride 17 (bank-spread)
  __shared__ float LsumS[64];
  __shared__ float u1A[32], cb1A[32], us1v[32], cs1v[32];
  __shared__ float u2gA[64], c2gA[64], u2sA[64], cs2A[64];

  const int tid = threadIdx.x;
  const int b = blockIdx.x;
  const int l = tid & 63, w = tid >> 6;
  const int p = w >> 1, h = w & 1;          // row-stripe / col-half
  const int q = l >> 4, c = l & 15;
  const int R = 16 * p;

  // ================= init 1: stage Lf, Xt (split), small weight folds ========
  const float* Lb = Lg + (size_t)b * 4096;
#pragma unroll
  for (int k = 0; k < 2; k++) {
    const int i4 = tid + 512 * k;                 // float4 index in [0,1024)
    const float4 v = *(const float4*)&Lb[i4 * 4];
    *(float4*)&Lf[(i4 >> 4) * LFS + (i4 & 15) * 4] = v;
  }
  const float* Xb = Xg + (size_t)b * 960;
  for (int i = tid; i < 960; i += 512) {
    const float x = Xb[i];
    const short hs = f2bs(x);
    const short ls = f2bs(x - bs2f(hs));
    XtHL[i] = ((unsigned int)(unsigned short)hs << 16) | (unsigned short)ls;
    Xtf[i] = x;
  }
  if (tid < 32) {
    const int f = tid;
    float a = 0.f, bb = 0.f, cc = 0.f, d = 0.f;
    for (int k = 0; k < 16; k++) {
      const float wp = Wp[k], bpv = bp[k];
      const float wg = Wg1[k * 32 + f], ws = Ws1[k * 32 + f];
      a += wp * wg; bb += bpv * wg;
      cc += wp * ws; d += bpv * ws;
    }
    u1A[f] = a; cb1A[f] = bb;
    us1v[f] = cc; cs1v[f] = d + bs1[f];
  }
  __syncthreads();

  // ================= init 2: Lsum, L A-frags, WgF, Ws2 frags ================
  {
    const int n = tid >> 3, o = tid & 7;
    const float4 a4 = *(const float4*)&Lf[n * LFS + 8 * o];
    const float4 b4 = *(const float4*)&Lf[n * LFS + 8 * o + 4];
    float ps = a4.x + a4.y + a4.z + a4.w + b4.x + b4.y + b4.z + b4.w;
    ps += __shfl_xor(ps, 1, 64);
    ps += __shfl_xor(ps, 2, 64);
    ps += __shfl_xor(ps, 4, 64);
    if (o == 0) LsumS[n] = ps;
  }
  // L A-frags: 3 parts x 2 K-slices (K=64)
  s16x8 Lh[2], Lm[2], Ll[2];
#pragma unroll
  for (int s = 0; s < 2; s++) {
    const float* rp = &Lf[(R + c) * LFS + 32 * s + 8 * q];
    const float4 v0 = *(const float4*)rp;
    const float4 v1 = *(const float4*)(rp + 4);
    float v[8] = {v0.x, v0.y, v0.z, v0.w, v1.x, v1.y, v1.z, v1.w};
#pragma unroll
    for (int j = 0; j < 8; j++) {
      const short hh = f2bs(v[j]);       const float r1 = v[j] - bs2f(hh);
      const short mm = f2bs(r1);         const float r2 = r1 - bs2f(mm);
      Lh[s][j] = hh; Lm[s][j] = mm; Ll[s][j] = f2bs(r2);
    }
  }
  // Wg2 fragment store: wave w builds tile tt=w&3; w<4 -> parts 0,1; w>=4 -> part 2
  {
    const int tt = w & 3;
    float v[8];
#pragma unroll
    for (int j = 0; j < 8; j++) v[j] = Wg2[(8 * q + j) * 64 + 16 * tt + c];
    if (w < 4) {
      s16x8 fh, fm;
#pragma unroll
      for (int j = 0; j < 8; j++) {
        const short hh = f2bs(v[j]);
        fh[j] = hh; fm[j] = f2bs(v[j] - bs2f(hh));
      }
      *(s16x8*)&WgF[((tt * 3 + 0) * 64 + l) * 8] = fh;
      *(s16x8*)&WgF[((tt * 3 + 1) * 64 + l) * 8] = fm;
    } else {
      s16x8 fl;
#pragma unroll
      for (int j = 0; j < 8; j++) {
        const short hh = f2bs(v[j]);     const float r1 = v[j] - bs2f(hh);
        const short mm = f2bs(r1);       const float r2 = r1 - bs2f(mm);
        fl[j] = f2bs(r2);
      }
      *(s16x8*)&WgF[((tt * 3 + 2) * 64 + l) * 8] = fl;
    }
  }
  // Ws2 frags (2-part) for this wave's two g-tiles, in registers
  s16x8 WsH[2], WsL[2];
#pragma unroll
  for (int i = 0; i < 2; i++) {
    const int g0 = 32 * h + 16 * i;
#pragma unroll
    for (int j = 0; j < 8; j++) {
      const float x = Ws2[(8 * q + j) * 64 + g0 + c];
      const short hh = f2bs(x);
      WsH[i][j] = hh; WsL[i][j] = f2bs(x - bs2f(hh));
    }
  }

  // ---- init 2b: LxAll[n][t] = (L @ Xt^T)[n][t] via ONE batched MFMA pass ----
  // B operand: col c = time-step (c<15; col 15 = copy of t=14, never read).
  // Accumulation chain textually identical to the per-step phase A ->
  // column t bit-identical. h==0 stores. Stride 17 spreads banks.
  {
    const f32x4 fz0 = {0.f, 0.f, 0.f, 0.f};
    f32x4 lxall = fz0;
    const int tc = c < 15 ? c : 14;    // clamp: col 15 = copy of t=14, unused
#pragma unroll
    for (int s = 0; s < 2; s++) {
      const unsigned int* xw = &XtHL[tc * 64 + 32 * s + 8 * q];
      const uint4 w0 = *(const uint4*)xw;
      const uint4 w1 = *(const uint4*)(xw + 4);
      unsigned int wv[8] = {w0.x, w0.y, w0.z, w0.w, w1.x, w1.y, w1.z, w1.w};
      s16x8 bh, bl;
#pragma unroll
      for (int j = 0; j < 8; j++) {
        bh[j] = (short)(wv[j] >> 16);
        bl[j] = (short)(wv[j] & 0xffff);
      }
      lxall = MFMA16(Lh[s], bh, lxall);
      lxall = MFMA16(Lm[s], bh, lxall);
      lxall = MFMA16(Lh[s], bl, lxall);
    }
    if (h == 0) {
#pragma unroll
      for (int r = 0; r < 4; r++) LxAll[(R + 4 * q + r) * 17 + c] = lxall[r];
    }
  }
  __syncthreads();

  // ================= init 3: layer-2 derived vectors =========================
  if (tid < 64) {
    const int g = tid;
    float a = 0.f, bb = 0.f, cc = 0.f, d = 0.f;
    for (int f = 0; f < 32; f++) {
      const float wg = Wg2[f * 64 + g], ws = Ws2[f * 64 + g];
      a += us1v[f] * wg; bb += cs1v[f] * wg;
      cc += us1v[f] * ws; d += cs1v[f] * ws;
    }
    u2gA[g] = a; c2gA[g] = bb; u2sA[g] = cc; cs2A[g] = d + bs2[g];
  }
  __syncthreads();

  // ================= init 4: per-lane constants (registers only) =============
  float u2g2[2], u2s2[2], cs22[2], c2c[2][4];
#pragma unroll
  for (int i = 0; i < 2; i++) {
    const int g = 32 * h + 16 * i + c;
    u2g2[i] = u2gA[g]; u2s2[i] = u2sA[g]; cs22[i] = cs2A[g];
    const float cg = c2gA[g], bg = bg2[g];
#pragma unroll
    for (int r = 0; r < 4; r++) c2c[i][r] = LsumS[R + 4 * q + r] * cg + bg;
  }
  // LIF-1 mapping (R17): thread (p,h,q,c) owns cells (rows R+4q+r, f2=16h+c)
  const int f2 = 16 * h + c;
  const float u1f = u1A[f2];
  float k1c[4];
  {
    const float cb = cb1A[f2], bg = bg1[f2];
#pragma unroll
    for (int r = 0; r < 4; r++) k1c[r] = LsumS[R + 4 * q + r] * cb + bg;
  }

  // ================= state registers =========================================
  float m1a[4], m1n[4], m1m[4];
#pragma unroll
  for (int j = 0; j < 4; j++) { m1a[j] = 0.f; m1n[j] = 0.f; m1m[j] = 0.f; }
  float m2a[2][4], m2n[2][4], m2m[2][4], mli[2][4], dpa[2][4];
#pragma unroll
  for (int i = 0; i < 2; i++)
#pragma unroll
    for (int r = 0; r < 4; r++) {
      m2a[i][r] = 0.f; m2n[i][r] = 0.f; m2m[i][r] = 0.f;
      mli[i][r] = 0.f; dpa[i][r] = 0.f;
    }

  const f32x4 fz = {0.f, 0.f, 0.f, 0.f};
  __syncthreads();   // Lf dead; UBUF becomes S1b/Mrow

  // ================= time loop: 2 barriers/step ==============================
  // Hazards (one barrier between reads and later writes suffices):
  //   B(t) S1b writes -> beta(t) -> C(t) S1b reads.
  //   C(t) S1b reads -> gamma(t) -> B(t+1) S1b writes.
  //   C(t) Mrow writes -> gamma(t) -> D(t) Mrow reads.
  //   D(t) Mrow reads -> beta(t+1) -> C(t+1) Mrow writes.
  // LxAll is read-only during the loop.
  for (int t = 0; t < 15; t++) {
    // ---- lx for this step: 4 broadcast LDS reads (phase A hoisted) ----
    float lxr[4];
#pragma unroll
    for (int r = 0; r < 4; r++) lxr[r] = LxAll[(R + 4 * q + r) * 17 + t];

    // ---- phase B: layer-1 LIF (register-only cur) -> S1b (bf16) ----
#pragma unroll
    for (int r = 0; r < 4; r++) {
      const float cur = lxr[r] * u1f + k1c[r];
      float ss = 0.f;
      LIF_STEP(m1a[r], 0.8f, 0.8f, cur, ss);
      LIF_STEP(m1n[r], 0.9f, 1.0f, cur, ss);
      LIF_STEP(m1m[r], 0.95f, 1.5f, cur, ss);
      S1b[(R + 4 * q + r) * RS + f2] = f2bs(ss);   // exact: ss in {0,1,2,3}
    }
    __syncthreads();   // beta

    // ---- phase C: M = L@S1 (3-part L), spk2d = S1@Ws2 (2-part W) ----
    f32x4 macc = fz;
#pragma unroll
    for (int s = 0; s < 2; s++) {
      s16x8 bS;
#pragma unroll
      for (int j = 0; j < 8; j++)
        bS[j] = S1b[(32 * s + 8 * q + j) * RS + 16 * h + c];
      macc = MFMA16(Lh[s], bS, macc);
      macc = MFMA16(Lm[s], bS, macc);
      macc = MFMA16(Ll[s], bS, macc);
    }
#pragma unroll
    for (int r = 0; r < 4; r++) Mrow[(R + 4 * q + r) * RS + 16 * h + c] = macc[r];

    f32x4 sacc[2];
    {
      const short* sp = &S1b[(R + c) * RS + 8 * q];
      s16x8 aS;
#pragma unroll
      for (int j = 0; j < 8; j++) aS[j] = sp[j];
#pragma unroll
      for (int i = 0; i < 2; i++) {
        sacc[i] = MFMA16(aS, WsH[i], fz);
        sacc[i] = MFMA16(aS, WsL[i], sacc[i]);
      }
    }
    __syncthreads();   // gamma

    // ---- phase D: cur2 = M@Wg2 (6-term) + LIF-2 (all in registers) ----
    s16x8 aMh, aMm, aMl;
    {
      const float* rp = &Mrow[(R + c) * RS + 8 * q];
      const float4 v0 = *(const float4*)rp;
      const float4 v1 = *(const float4*)(rp + 4);
      const float v[8] = {v0.x, v0.y, v0.z, v0.w, v1.x, v1.y, v1.z, v1.w};
#pragma unroll
      for (int j = 0; j < 8; j++) {
        const short hh = f2bs(v[j]);     const float r1 = v[j] - bs2f(hh);
        const short mm = f2bs(r1);       const float r2 = r1 - bs2f(mm);
        aMh[j] = hh; aMm[j] = mm; aMl[j] = f2bs(r2);
      }
    }
    float xtn[4];
#pragma unroll
    for (int r = 0; r < 4; r++) xtn[r] = Xtf[t * 64 + R + 4 * q + r];

#pragma unroll
    for (int i = 0; i < 2; i++) {
      const int tt = 2 * h + i;
      const s16x8 bGh = *(const s16x8*)&WgF[((tt * 3 + 0) * 64 + l) * 8];
      const s16x8 bGm = *(const s16x8*)&WgF[((tt * 3 + 1) * 64 + l) * 8];
      const s16x8 bGl = *(const s16x8*)&WgF[((tt * 3 + 2) * 64 + l) * 8];
      f32x4 cacc = fz;
      cacc = MFMA16(aMh, bGh, cacc);
      cacc = MFMA16(aMh, bGm, cacc);
      cacc = MFMA16(aMm, bGh, cacc);
      cacc = MFMA16(aMh, bGl, cacc);
      cacc = MFMA16(aMm, bGm, cacc);
      cacc = MFMA16(aMl, bGh, cacc);
#pragma unroll
      for (int r = 0; r < 4; r++) {
        const float cur2 = cacc[r] + lxr[r] * u2g2[i] + c2c[i][r];
        float ss = 0.f;
        LIF_STEP(m2a[i][r], 0.8f, 0.8f, cur2, ss);
        LIF_STEP(m2n[i][r], 0.9f, 1.0f, cur2, ss);
        LIF_STEP(m2m[i][r], 0.95f, 1.5f, cur2, ss);
        const float spk2 = ss + sacc[i][r] + xtn[r] * u2s2[i] + cs22[i];
        mli[i][r] = 0.9f * mli[i][r] + spk2;
      }
    }
    if (t < 5) {
#pragma unroll
      for (int i = 0; i < 2; i++)
#pragma unroll
        for (int r = 0; r < 4; r++) dpa[i][r] -= mli[i][r];
    } else if (t >= 10) {
#pragma unroll
      for (int i = 0; i < 2; i++)
#pragma unroll
        for (int r = 0; r < 4; r++) dpa[i][r] += mli[i][r];
    }
    // no end-of-step barrier (gamma(t) + beta(t+1) cover all hazards)
  }

  // ---- dp_feat = (sum_last5 - sum_first5)/5, packed split-bf16 ----
  unsigned int* dpb = dp_out + (size_t)b * 4096;
#pragma unroll
  for (int i = 0; i < 2; i++) {
    const int g = 32 * h + 16 * i + c;
#pragma unroll
    for (int r = 0; r < 4; r++) {
      const int n = R + 4 * q + r;
      const float v = dpa[i][r] * 0.2f;
      const short hh = f2bs(v);
      const short ll = f2bs(v - bs2f(hh));
      dpb[n * 64 + g] = ((unsigned int)(unsigned short)hh << 16) | (unsigned short)ll;
    }
  }
}

// Decoder v2 (R10 champion, verbatim): out = relu(dp @ W1 + b1) @ W2 + b2.
// 256 blocks x 512 threads (8 waves = 2/SIMD). Block = (16-batch group g) x
// (64-col half hb). Wave (tw, kh): col sub-tile tw, K-half kh (64 slices).
// Partial acc -> LDS Hp[2], one barrier, bias+relu+GEMM2. Second GEMM:
// 64-col partial per block via f32 atomicAdd (2 commutative contributions
// per element; out zeroed by hipMemsetAsync; each block adds b2/2).

#define DEC_STEP(S, CA0, CA1)                                          \
  {                                                                    \
    const unsigned int av[8] = {(CA0).x, (CA0).y, (CA0).z, (CA0).w,    \
                                (CA1).x, (CA1).y, (CA1).z, (CA1).w};   \
    s16x8 Ah, Al, Bh, Bl;                                              \
    _Pragma("unroll")                                                  \
    for (int j = 0; j < 8; j++) {                                      \
      Ah[j] = (short)(av[j] >> 16);                                    \
      Al[j] = (short)(av[j] & 0xffff);                                 \
      const float x = bcol2[(32 * (S) + j) * 128];                     \
      const short hh = f2bs(x);                                        \
      Bh[j] = hh; Bl[j] = f2bs(x - bs2f(hh));                          \
    }                                                                  \
    acc = MFMA16(Ah, Bh, acc);                                         \
    acc = MFMA16(Al, Bh, acc);                                         \
    acc = MFMA16(Ah, Bl, acc);                                         \
  }

#define DEC_SLOT(S, BUF, NXT)                                          \
  {                                                                    \
    const uint4 c0 = BUF[0], c1 = BUF[1];                              \
    if ((NXT) < 64) {                                                  \
      BUF[0] = *(const uint4*)(arow2 + 32 * (NXT));                    \
      BUF[1] = *(const uint4*)(arow2 + 32 * (NXT) + 4);                \
    }                                                                  \
    DEC_STEP(S, c0, c1);                                               \
  }

__global__ __launch_bounds__(512, 2)
void hrsnn_decoder(const unsigned int* __restrict__ dpq, const float* __restrict__ W1,
                   const float* __restrict__ b1, const float* __restrict__ W2,
                   const float* __restrict__ b2, float* __restrict__ out)
{
  __shared__ __align__(16) float Hp[2][16][68];   // partial acc per K-half
  const int tid = threadIdx.x;
  const int l = tid & 63, w = tid >> 6;
  const int tw = w & 3, kh = w >> 2;           // col sub-tile / K half
  const int g  = blockIdx.x >> 1;              // batch group (16 rows)
  const int hb = blockIdx.x & 1;               // col half (64 of 128)
  const int q = l >> 4, c = l & 15;
  const int col = 64 * hb + 16 * tw + c;

  const unsigned int* arow2 = dpq + (size_t)(g * 16 + c) * 4096 + 2048 * kh + 8 * q;
  const float* bcol2 = W1 + (size_t)(2048 * kh + 8 * q) * 128 + col;

  f32x4 acc = {0.f, 0.f, 0.f, 0.f};
  uint4 A0[2], A1[2], A2[2], A3[2];
  A0[0] = *(const uint4*)(arow2);       A0[1] = *(const uint4*)(arow2 + 4);
  A1[0] = *(const uint4*)(arow2 + 32);  A1[1] = *(const uint4*)(arow2 + 36);
  A2[0] = *(const uint4*)(arow2 + 64);  A2[1] = *(const uint4*)(arow2 + 68);
  A3[0] = *(const uint4*)(arow2 + 96);  A3[1] = *(const uint4*)(arow2 + 100);
  for (int sl = 0; sl < 64; sl += 4) {
    DEC_SLOT(sl,     A0, sl + 4);
    DEC_SLOT(sl + 1, A1, sl + 5);
    DEC_SLOT(sl + 2, A2, sl + 6);
    DEC_SLOT(sl + 3, A3, sl + 7);
  }

#pragma unroll
  for (int r = 0; r < 4; r++) Hp[kh][4 * q + r][16 * tw + c] = acc[r];
  __syncthreads();

  if (tid < 64) {
    const int i = tid >> 2, o = tid & 3;
    float s = 0.5f * b2[o];
    const float* b1h = b1 + 64 * hb;
    const float* w2 = W2 + (64 * hb) * 4 + o;
    for (int k = 0; k < 64; k++) {
      float hv = Hp[0][i][k] + Hp[1][i][k] + b1h[k];
      hv = hv > 0.f ? hv : 0.f;
      s += hv * w2[k * 4];
    }
    atomicAdd(&out[(size_t)(g * 16 + i) * 4 + o], s);
  }
}

extern "C" void kernel_launch(void* const* d_in, const int* in_sizes, int n_in,
                              void* d_out, int out_size, void* d_ws, size_t ws_size,
                              hipStream_t stream)
{
  const float* Lg  = (const float*)d_in[0];
  const float* Xg  = (const float*)d_in[1];
  const float* Wp  = (const float*)d_in[2];
  const float* bp  = (const float*)d_in[3];
  const float* Wg1 = (const float*)d_in[4];
  const float* bg1 = (const float*)d_in[5];
  const float* Ws1 = (const float*)d_in[6];
  const float* bs1 = (const float*)d_in[7];
  const float* Wg2 = (const float*)d_in[8];
  const float* bg2 = (const float*)d_in[9];
  const float* Ws2 = (const float*)d_in[10];
  const float* bs2 = (const float*)d_in[11];
  const float* W1  = (const float*)d_in[12];
  const float* b1  = (const float*)d_in[13];
  const float* W2  = (const float*)d_in[14];
  const float* b2  = (const float*)d_in[15];

  unsigned int* dpq = (unsigned int*)d_ws;  // 2048*4096 packed uint = 32 MB
  float* out = (float*)d_out;               // [2048, 4] f32

  hipLaunchKernelGGL(hrsnn_main, dim3(2048), dim3(512), 0, stream,
                     Lg, Xg, Wp, bp, Wg1, bg1, Ws1, bs1, Wg2, bg2, Ws2, bs2, dpq);
  hipMemsetAsync(out, 0, (size_t)2048 * 4 * sizeof(float), stream);
  hipLaunchKernelGGL(hrsnn_decoder, dim3(256), dim3(512), 0, stream,
                     dpq, W1, b1, W2, b2, out);
}

// Round 16
// 402.884 us; speedup vs baseline: 1.9559x; 1.0185x over previous
//
#include <hip/hip_runtime.h>
#include <hip/hip_bf16.h>

// RiemannianGraph_HRSNN, MFMA version. B=2048, T=15, N=64. All I/O f32.
// R21: PRODUCER-SIDE M-SPLIT. R20 = 410.33us champion (main 302us, VALU
// 51% at 23% occupancy). Phase D's 3-part split of M ran REDUNDANTLY: the
// two h-waves of each stripe split the same 2048 M-elements twice (4096
// chains/block-step, ~10 serial VALU each, on D's critical path). R21
// splits in phase C where each producer thread holds its 4 macc[r] values
// (1:1, 2048 chains) and stores M as 3 pre-split bf16 parts
// MS[3][64][40] shorts (stride 40 -> 80B rows, 16B-aligned b128, <=2-way
// banks). Phase D: 3x ds_read_b128, ZERO conversions. Bit-identity: split
// expressions textually identical on the identical f32 (macc[r] = old
// Mrow value); both h-waves previously produced identical splits, so
// single-producer preserves bits. Hazards unchanged (C writes MS ->
// gamma -> D reads; D reads -> beta(t+1) -> C(t+1) writes). Mrow deleted;
// UBUF 4992 f32. Same (512,2) 2-barrier class (absmax 0.375 preserved in
// R15/R17/R19/R20). Decoder: R10 verbatim.
//
// Main-kernel math (unchanged from R4):
//   L 3-part x S1(exact)            -> 2^-27
//   M 3-part x Wg2 3-part (6 terms) -> ~2^-24
//   S1(exact) x Ws2 2-part          -> 2^-18 (no threshold downstream)
//   L 3-part x Xt 2-part (3 terms)  -> ~2^-17
// MFMA layouts: A[row=lane&15][k=8*(lane>>4)+j], B[k=8q+j][col=lane&15],
// C/D[row=4*(lane>>4)+reg][col=lane&15].

typedef __attribute__((ext_vector_type(8))) short s16x8;
typedef __attribute__((ext_vector_type(4))) float f32x4;
#define MFMA16(a, b, c) __builtin_amdgcn_mfma_f32_16x16x32_bf16(a, b, c, 0, 0, 0)

__device__ __forceinline__ short f2bs(float x) {
  union { __hip_bfloat16 h; short s; } u; u.h = __float2bfloat16(x); return u.s;
}
__device__ __forceinline__ float bs2f(short s) {
  union { short s; __hip_bfloat16 h; } u; u.s = s; return __bfloat162float(u.h);
}

#define LIF_STEP(mem, beta, thr, cur, spksum)                \
  {                                                          \
    float r_ = ((mem) > (thr)) ? (thr) : 0.0f;               \
    (mem) = (beta) * (mem) + (cur) - r_;                     \
    (spksum) += (((mem) - (thr)) > 0.0f) ? 1.0f : 0.0f;      \
  }

#define LFS 68      // Lf row stride (f32 words)
#define RS  36      // S1b row stride (shorts)
#define MSR 40      // MS row stride (shorts): 80B rows, 16B-aligned
#define MSP 2560    // MS part stride (shorts): 64*40

__global__ __launch_bounds__(512, 2)
void hrsnn_main(const float* __restrict__ Lg,  const float* __restrict__ Xg,
                const float* __restrict__ Wp,  const float* __restrict__ bp,
                const float* __restrict__ Wg1, const float* __restrict__ bg1,
                const float* __restrict__ Ws1, const float* __restrict__ bs1,
                const float* __restrict__ Wg2, const float* __restrict__ bg2,
                const float* __restrict__ Ws2, const float* __restrict__ bs2,
                unsigned int* __restrict__ dp_out)
{
  // UBUF: union of Lf[64][68] f32 (init only, 17408B) with
  //   S1b[64][36] shorts (4608B) + MS[3][64][40] shorts (15360B at +4608B).
  __shared__ __align__(16) float UBUF[4992];
  float* const Lf   = UBUF;                 // init only
  short* const S1b  = (short*)UBUF;         // [64][RS] shorts (spike sums, bf16)
  short* const MSb  = (short*)UBUF + 2304;  // [3][64][MSR] shorts (M split parts)
  __shared__ __align__(16) short WgF[4 * 3 * 64 * 8];   // Wg2 frags [tile][part][lane][8]
  __shared__ __align__(16) unsigned int XtHL[960];      // packed (hi<<16|lo) bf16 of Xt
  __shared__ __align__(16) float Xtf[960];
  __shared__ __align__(16) float LxAll[1088];           // Lx[n][t], stride 17 (bank-spread)
  __shared__ float LsumS[64];
  __shared__ float u1A[32], cb1A[32], us1v[32], cs1v[32];
  __shared__ float u2gA[64], c2gA[64], u2sA[64], cs2A[64];

  const int tid = threadIdx.x;
  const int b = blockIdx.x;
  const int l = tid & 63, w = tid >> 6;
  const int p = w >> 1, h = w & 1;          // row-stripe / col-half
  const int q = l >> 4, c = l & 15;
  const int R = 16 * p;

  // ================= init 1: stage Lf, Xt (split), small weight folds ========
  const float* Lb = Lg + (size_t)b * 4096;
#pragma unroll
  for (int k = 0; k < 2; k++) {
    const int i4 = tid + 512 * k;                 // float4 index in [0,1024)
    const float4 v = *(const float4*)&Lb[i4 * 4];
    *(float4*)&Lf[(i4 >> 4) * LFS + (i4 & 15) * 4] = v;
  }
  const float* Xb = Xg + (size_t)b * 960;
  for (int i = tid; i < 960; i += 512) {
    const float x = Xb[i];
    const short hs = f2bs(x);
    const short ls = f2bs(x - bs2f(hs));
    XtHL[i] = ((unsigned int)(unsigned short)hs << 16) | (unsigned short)ls;
    Xtf[i] = x;
  }
  if (tid < 32) {
    const int f = tid;
    float a = 0.f, bb = 0.f, cc = 0.f, d = 0.f;
    for (int k = 0; k < 16; k++) {
      const float wp = Wp[k], bpv = bp[k];
      const float wg = Wg1[k * 32 + f], ws = Ws1[k * 32 + f];
      a += wp * wg; bb += bpv * wg;
      cc += wp * ws; d += bpv * ws;
    }
    u1A[f] = a; cb1A[f] = bb;
    us1v[f] = cc; cs1v[f] = d + bs1[f];
  }
  __syncthreads();

  // ================= init 2: Lsum, L A-frags, WgF, Ws2 frags ================
  {
    const int n = tid >> 3, o = tid & 7;
    const float4 a4 = *(const float4*)&Lf[n * LFS + 8 * o];
    const float4 b4 = *(const float4*)&Lf[n * LFS + 8 * o + 4];
    float ps = a4.x + a4.y + a4.z + a4.w + b4.x + b4.y + b4.z + b4.w;
    ps += __shfl_xor(ps, 1, 64);
    ps += __shfl_xor(ps, 2, 64);
    ps += __shfl_xor(ps, 4, 64);
    if (o == 0) LsumS[n] = ps;
  }
  // L A-frags: 3 parts x 2 K-slices (K=64)
  s16x8 Lh[2], Lm[2], Ll[2];
#pragma unroll
  for (int s = 0; s < 2; s++) {
    const float* rp = &Lf[(R + c) * LFS + 32 * s + 8 * q];
    const float4 v0 = *(const float4*)rp;
    const float4 v1 = *(const float4*)(rp + 4);
    float v[8] = {v0.x, v0.y, v0.z, v0.w, v1.x, v1.y, v1.z, v1.w};
#pragma unroll
    for (int j = 0; j < 8; j++) {
      const short hh = f2bs(v[j]);       const float r1 = v[j] - bs2f(hh);
      const short mm = f2bs(r1);         const float r2 = r1 - bs2f(mm);
      Lh[s][j] = hh; Lm[s][j] = mm; Ll[s][j] = f2bs(r2);
    }
  }
  // Wg2 fragment store: wave w builds tile tt=w&3; w<4 -> parts 0,1; w>=4 -> part 2
  {
    const int tt = w & 3;
    float v[8];
#pragma unroll
    for (int j = 0; j < 8; j++) v[j] = Wg2[(8 * q + j) * 64 + 16 * tt + c];
    if (w < 4) {
      s16x8 fh, fm;
#pragma unroll
      for (int j = 0; j < 8; j++) {
        const short hh = f2bs(v[j]);
        fh[j] = hh; fm[j] = f2bs(v[j] - bs2f(hh));
      }
      *(s16x8*)&WgF[((tt * 3 + 0) * 64 + l) * 8] = fh;
      *(s16x8*)&WgF[((tt * 3 + 1) * 64 + l) * 8] = fm;
    } else {
      s16x8 fl;
#pragma unroll
      for (int j = 0; j < 8; j++) {
        const short hh = f2bs(v[j]);     const float r1 = v[j] - bs2f(hh);
        const short mm = f2bs(r1);       const float r2 = r1 - bs2f(mm);
        fl[j] = f2bs(r2);
      }
      *(s16x8*)&WgF[((tt * 3 + 2) * 64 + l) * 8] = fl;
    }
  }
  // Ws2 frags (2-part) for this wave's two g-tiles, in registers
  s16x8 WsH[2], WsL[2];
#pragma unroll
  for (int i = 0; i < 2; i++) {
    const int g0 = 32 * h + 16 * i;
#pragma unroll
    for (int j = 0; j < 8; j++) {
      const float x = Ws2[(8 * q + j) * 64 + g0 + c];
      const short hh = f2bs(x);
      WsH[i][j] = hh; WsL[i][j] = f2bs(x - bs2f(hh));
    }
  }

  // ---- init 2b: LxAll[n][t] = (L @ Xt^T)[n][t] via ONE batched MFMA pass ----
  // B operand: col c = time-step (c<15; col 15 = copy of t=14, never read).
  // Accumulation chain textually identical to the per-step phase A ->
  // column t bit-identical. h==0 stores. Stride 17 spreads banks.
  {
    const f32x4 fz0 = {0.f, 0.f, 0.f, 0.f};
    f32x4 lxall = fz0;
    const int tc = c < 15 ? c : 14;    // clamp: col 15 = copy of t=14, unused
#pragma unroll
    for (int s = 0; s < 2; s++) {
      const unsigned int* xw = &XtHL[tc * 64 + 32 * s + 8 * q];
      const uint4 w0 = *(const uint4*)xw;
      const uint4 w1 = *(const uint4*)(xw + 4);
      unsigned int wv[8] = {w0.x, w0.y, w0.z, w0.w, w1.x, w1.y, w1.z, w1.w};
      s16x8 bh, bl;
#pragma unroll
      for (int j = 0; j < 8; j++) {
        bh[j] = (short)(wv[j] >> 16);
        bl[j] = (short)(wv[j] & 0xffff);
      }
      lxall = MFMA16(Lh[s], bh, lxall);
      lxall = MFMA16(Lm[s], bh, lxall);
      lxall = MFMA16(Lh[s], bl, lxall);
    }
    if (h == 0) {
#pragma unroll
      for (int r = 0; r < 4; r++) LxAll[(R + 4 * q + r) * 17 + c] = lxall[r];
    }
  }
  __syncthreads();

  // ================= init 3: layer-2 derived vectors =========================
  if (tid < 64) {
    const int g = tid;
    float a = 0.f, bb = 0.f, cc = 0.f, d = 0.f;
    for (int f = 0; f < 32; f++) {
      const float wg = Wg2[f * 64 + g], ws = Ws2[f * 64 + g];
      a += us1v[f] * wg; bb += cs1v[f] * wg;
      cc += us1v[f] * ws; d += cs1v[f] * ws;
    }
    u2gA[g] = a; c2gA[g] = bb; u2sA[g] = cc; cs2A[g] = d + bs2[g];
  }
  __syncthreads();

  // ================= init 4: per-lane constants (registers only) =============
  float u2g2[2], u2s2[2], cs22[2], c2c[2][4];
#pragma unroll
  for (int i = 0; i < 2; i++) {
    const int g = 32 * h + 16 * i + c;
    u2g2[i] = u2gA[g]; u2s2[i] = u2sA[g]; cs22[i] = cs2A[g];
    const float cg = c2gA[g], bg = bg2[g];
#pragma unroll
    for (int r = 0; r < 4; r++) c2c[i][r] = LsumS[R + 4 * q + r] * cg + bg;
  }
  // LIF-1 mapping (R17): thread (p,h,q,c) owns cells (rows R+4q+r, f2=16h+c)
  const int f2 = 16 * h + c;
  const float u1f = u1A[f2];
  float k1c[4];
  {
    const float cb = cb1A[f2], bg = bg1[f2];
#pragma unroll
    for (int r = 0; r < 4; r++) k1c[r] = LsumS[R + 4 * q + r] * cb + bg;
  }

  // ================= state registers =========================================
  float m1a[4], m1n[4], m1m[4];
#pragma unroll
  for (int j = 0; j < 4; j++) { m1a[j] = 0.f; m1n[j] = 0.f; m1m[j] = 0.f; }
  float m2a[2][4], m2n[2][4], m2m[2][4], mli[2][4], dpa[2][4];
#pragma unroll
  for (int i = 0; i < 2; i++)
#pragma unroll
    for (int r = 0; r < 4; r++) {
      m2a[i][r] = 0.f; m2n[i][r] = 0.f; m2m[i][r] = 0.f;
      mli[i][r] = 0.f; dpa[i][r] = 0.f;
    }

  const f32x4 fz = {0.f, 0.f, 0.f, 0.f};
  __syncthreads();   // Lf dead; UBUF becomes S1b/MS

  // ================= time loop: 2 barriers/step ==============================
  // Hazards (one barrier between reads and later writes suffices):
  //   B(t) S1b writes -> beta(t) -> C(t) S1b reads.
  //   C(t) S1b reads -> gamma(t) -> B(t+1) S1b writes.
  //   C(t) MS writes -> gamma(t) -> D(t) MS reads.
  //   D(t) MS reads -> beta(t+1) -> C(t+1) MS writes.
  // LxAll is read-only during the loop.
  for (int t = 0; t < 15; t++) {
    // ---- lx for this step: 4 broadcast LDS reads (phase A hoisted) ----
    float lxr[4];
#pragma unroll
    for (int r = 0; r < 4; r++) lxr[r] = LxAll[(R + 4 * q + r) * 17 + t];

    // ---- phase B: layer-1 LIF (register-only cur) -> S1b (bf16) ----
#pragma unroll
    for (int r = 0; r < 4; r++) {
      const float cur = lxr[r] * u1f + k1c[r];
      float ss = 0.f;
      LIF_STEP(m1a[r], 0.8f, 0.8f, cur, ss);
      LIF_STEP(m1n[r], 0.9f, 1.0f, cur, ss);
      LIF_STEP(m1m[r], 0.95f, 1.5f, cur, ss);
      S1b[(R + 4 * q + r) * RS + f2] = f2bs(ss);   // exact: ss in {0,1,2,3}
    }
    __syncthreads();   // beta

    // ---- phase C: M = L@S1 (3-part L) SPLIT AT PRODUCER; spk2d = S1@Ws2 ----
    f32x4 macc = fz;
#pragma unroll
    for (int s = 0; s < 2; s++) {
      s16x8 bS;
#pragma unroll
      for (int j = 0; j < 8; j++)
        bS[j] = S1b[(32 * s + 8 * q + j) * RS + 16 * h + c];
      macc = MFMA16(Lh[s], bS, macc);
      macc = MFMA16(Lm[s], bS, macc);
      macc = MFMA16(Ll[s], bS, macc);
    }
    // 3-way split of each produced element (identical expression form to the
    // old consumer-side split, same f32 input -> bit-identical parts).
#pragma unroll
    for (int r = 0; r < 4; r++) {
      const float v = macc[r];
      const short hh = f2bs(v);     const float r1 = v - bs2f(hh);
      const short mm = f2bs(r1);    const float r2 = r1 - bs2f(mm);
      const short ll = f2bs(r2);
      const int o = (R + 4 * q + r) * MSR + 16 * h + c;
      MSb[o] = hh; MSb[MSP + o] = mm; MSb[2 * MSP + o] = ll;
    }

    f32x4 sacc[2];
    {
      const short* sp = &S1b[(R + c) * RS + 8 * q];
      s16x8 aS;
#pragma unroll
      for (int j = 0; j < 8; j++) aS[j] = sp[j];
#pragma unroll
      for (int i = 0; i < 2; i++) {
        sacc[i] = MFMA16(aS, WsH[i], fz);
        sacc[i] = MFMA16(aS, WsL[i], sacc[i]);
      }
    }
    __syncthreads();   // gamma

    // ---- phase D: cur2 = M@Wg2 (6-term) + LIF-2; M parts pre-split ----
    const int ro = (R + c) * MSR + 8 * q;
    const s16x8 aMh = *(const s16x8*)&MSb[ro];
    const s16x8 aMm = *(const s16x8*)&MSb[MSP + ro];
    const s16x8 aMl = *(const s16x8*)&MSb[2 * MSP + ro];
    float xtn[4];
#pragma unroll
    for (int r = 0; r < 4; r++) xtn[r] = Xtf[t * 64 + R + 4 * q + r];

#pragma unroll
    for (int i = 0; i < 2; i++) {
      const int tt = 2 * h + i;
      const s16x8 bGh = *(const s16x8*)&WgF[((tt * 3 + 0) * 64 + l) * 8];
      const s16x8 bGm = *(const s16x8*)&WgF[((tt * 3 + 1) * 64 + l) * 8];
      const s16x8 bGl = *(const s16x8*)&WgF[((tt * 3 + 2) * 64 + l) * 8];
      f32x4 cacc = fz;
      cacc = MFMA16(aMh, bGh, cacc);
      cacc = MFMA16(aMh, bGm, cacc);
      cacc = MFMA16(aMm, bGh, cacc);
      cacc = MFMA16(aMh, bGl, cacc);
      cacc = MFMA16(aMm, bGm, cacc);
      cacc = MFMA16(aMl, bGh, cacc);
#pragma unroll
      for (int r = 0; r < 4; r++) {
        const float cur2 = cacc[r] + lxr[r] * u2g2[i] + c2c[i][r];
        float ss = 0.f;
        LIF_STEP(m2a[i][r], 0.8f, 0.8f, cur2, ss);
        LIF_STEP(m2n[i][r], 0.9f, 1.0f, cur2, ss);
        LIF_STEP(m2m[i][r], 0.95f, 1.5f, cur2, ss);
        const float spk2 = ss + sacc[i][r] + xtn[r] * u2s2[i] + cs22[i];
        mli[i][r] = 0.9f * mli[i][r] + spk2;
      }
    }
    if (t < 5) {
#pragma unroll
      for (int i = 0; i < 2; i++)
#pragma unroll
        for (int r = 0; r < 4; r++) dpa[i][r] -= mli[i][r];
    } else if (t >= 10) {
#pragma unroll
      for (int i = 0; i < 2; i++)
#pragma unroll
        for (int r = 0; r < 4; r++) dpa[i][r] += mli[i][r];
    }
    // no end-of-step barrier (gamma(t) + beta(t+1) cover all hazards)
  }

  // ---- dp_feat = (sum_last5 - sum_first5)/5, packed split-bf16 ----
  unsigned int* dpb = dp_out + (size_t)b * 4096;
#pragma unroll
  for (int i = 0; i < 2; i++) {
    const int g = 32 * h + 16 * i + c;
#pragma unroll
    for (int r = 0; r < 4; r++) {
      const int n = R + 4 * q + r;
      const float v = dpa[i][r] * 0.2f;
      const short hh = f2bs(v);
      const short ll = f2bs(v - bs2f(hh));
      dpb[n * 64 + g] = ((unsigned int)(unsigned short)hh << 16) | (unsigned short)ll;
    }
  }
}

// Decoder v2 (R10 champion, verbatim): out = relu(dp @ W1 + b1) @ W2 + b2.
// 256 blocks x 512 threads (8 waves = 2/SIMD). Block = (16-batch group g) x
// (64-col half hb). Wave (tw, kh): col sub-tile tw, K-half kh (64 slices).
// Partial acc -> LDS Hp[2], one barrier, bias+relu+GEMM2. Second GEMM:
// 64-col partial per block via f32 atomicAdd (2 commutative contributions
// per element; out zeroed by hipMemsetAsync; each block adds b2/2).

#define DEC_STEP(S, CA0, CA1)                                          \
  {                                                                    \
    const unsigned int av[8] = {(CA0).x, (CA0).y, (CA0).z, (CA0).w,    \
                                (CA1).x, (CA1).y, (CA1).z, (CA1).w};   \
    s16x8 Ah, Al, Bh, Bl;                                              \
    _Pragma("unroll")                                                  \
    for (int j = 0; j < 8; j++) {                                      \
      Ah[j] = (short)(av[j] >> 16);                                    \
      Al[j] = (short)(av[j] & 0xffff);                                 \
      const float x = bcol2[(32 * (S) + j) * 128];                     \
      const short hh = f2bs(x);                                        \
      Bh[j] = hh; Bl[j] = f2bs(x - bs2f(hh));                          \
    }                                                                  \
    acc = MFMA16(Ah, Bh, acc);                                         \
    acc = MFMA16(Al, Bh, acc);                                         \
    acc = MFMA16(Ah, Bl, acc);                                         \
  }

#define DEC_SLOT(S, BUF, NXT)                                          \
  {                                                                    \
    const uint4 c0 = BUF[0], c1 = BUF[1];                              \
    if ((NXT) < 64) {                                                  \
      BUF[0] = *(const uint4*)(arow2 + 32 * (NXT));                    \
      BUF[1] = *(const uint4*)(arow2 + 32 * (NXT) + 4);                \
    }                                                                  \
    DEC_STEP(S, c0, c1);                                               \
  }

__global__ __launch_bounds__(512, 2)
void hrsnn_decoder(const unsigned int* __restrict__ dpq, const float* __restrict__ W1,
                   const float* __restrict__ b1, const float* __restrict__ W2,
                   const float* __restrict__ b2, float* __restrict__ out)
{
  __shared__ __align__(16) float Hp[2][16][68];   // partial acc per K-half
  const int tid = threadIdx.x;
  const int l = tid & 63, w = tid >> 6;
  const int tw = w & 3, kh = w >> 2;           // col sub-tile / K half
  const int g  = blockIdx.x >> 1;              // batch group (16 rows)
  const int hb = blockIdx.x & 1;               // col half (64 of 128)
  const int q = l >> 4, c = l & 15;
  const int col = 64 * hb + 16 * tw + c;

  const unsigned int* arow2 = dpq + (size_t)(g * 16 + c) * 4096 + 2048 * kh + 8 * q;
  const float* bcol2 = W1 + (size_t)(2048 * kh + 8 * q) * 128 + col;

  f32x4 acc = {0.f, 0.f, 0.f, 0.f};
  uint4 A0[2], A1[2], A2[2], A3[2];
  A0[0] = *(const uint4*)(arow2);       A0[1] = *(const uint4*)(arow2 + 4);
  A1[0] = *(const uint4*)(arow2 + 32);  A1[1] = *(const uint4*)(arow2 + 36);
  A2[0] = *(const uint4*)(arow2 + 64);  A2[1] = *(const uint4*)(arow2 + 68);
  A3[0] = *(const uint4*)(arow2 + 96);  A3[1] = *(const uint4*)(arow2 + 100);
  for (int sl = 0; sl < 64; sl += 4) {
    DEC_SLOT(sl,     A0, sl + 4);
    DEC_SLOT(sl + 1, A1, sl + 5);
    DEC_SLOT(sl + 2, A2, sl + 6);
    DEC_SLOT(sl + 3, A3, sl + 7);
  }

#pragma unroll
  for (int r = 0; r < 4; r++) Hp[kh][4 * q + r][16 * tw + c] = acc[r];
  __syncthreads();

  if (tid < 64) {
    const int i = tid >> 2, o = tid & 3;
    float s = 0.5f * b2[o];
    const float* b1h = b1 + 64 * hb;
    const float* w2 = W2 + (64 * hb) * 4 + o;
    for (int k = 0; k < 64; k++) {
      float hv = Hp[0][i][k] + Hp[1][i][k] + b1h[k];
      hv = hv > 0.f ? hv : 0.f;
      s += hv * w2[k * 4];
    }
    atomicAdd(&out[(size_t)(g * 16 + i) * 4 + o], s);
  }
}

extern "C" void kernel_launch(void* const* d_in, const int* in_sizes, int n_in,
                              void* d_out, int out_size, void* d_ws, size_t ws_size,
                              hipStream_t stream)
{
  const float* Lg  = (const float*)d_in[0];
  const float* Xg  = (const float*)d_in[1];
  const float* Wp  = (const float*)d_in[2];
  const float* bp  = (const float*)d_in[3];
  const float* Wg1 = (const float*)d_in[4];
  const float* bg1 = (const float*)d_in[5];
  const float* Ws1 = (const float*)d_in[6];
  const float* bs1 = (const float*)d_in[7];
  const float* Wg2 = (const float*)d_in[8];
  const float* bg2 = (const float*)d_in[9];
  const float* Ws2 = (const float*)d_in[10];
  const float* bs2 = (const float*)d_in[11];
  const float* W1  = (const float*)d_in[12];
  const float* b1  = (const float*)d_in[13];
  const float* W2  = (const float*)d_in[14];
  const float* b2  = (const float*)d_in[15];

  unsigned int* dpq = (unsigned int*)d_ws;  // 2048*4096 packed uint = 32 MB
  float* out = (float*)d_out;               // [2048, 4] f32

  hipLaunchKernelGGL(hrsnn_main, dim3(2048), dim3(512), 0, stream,
                     Lg, Xg, Wp, bp, Wg1, bg1, Ws1, bs1, Wg2, bg2, Ws2, bs2, dpq);
  hipMemsetAsync(out, 0, (size_t)2048 * 4 * sizeof(float), stream);
  hipLaunchKernelGGL(hrsnn_decoder, dim3(256), dim3(512), 0, stream,
                     dpq, W1, b1, W2, b2, out);
}